// Round 5
// baseline (1461.166 us; speedup 1.0000x reference)
//
#include <hip/hip_runtime.h>
#include <cstdint>
#include <cstddef>

typedef unsigned int u32;
typedef unsigned short u16;
typedef long long i64;

typedef __attribute__((ext_vector_type(8))) short short8;
typedef __attribute__((ext_vector_type(4))) float f32x4;
typedef __attribute__((ext_vector_type(4))) int i32x4;

// ---------------- device helpers ----------------
__device__ __forceinline__ u16 f2bf(float f) {
  u32 u = __float_as_uint(f);
  u = (u + 0x7FFFu + ((u >> 16) & 1u)) >> 16;  // RNE
  return (u16)u;
}
__device__ __forceinline__ float bf2f(u16 h) { return __uint_as_float(((u32)h) << 16); }

__device__ __forceinline__ short8 neg8(short8 v) {
  i32x4 u = __builtin_bit_cast(i32x4, v);
  u = u ^ (int)0x80008000u;
  return __builtin_bit_cast(short8, u);
}
__device__ __forceinline__ f32x4 mfma16(short8 a, short8 b, f32x4 c) {
  return __builtin_amdgcn_mfma_f32_16x16x32_bf16(a, b, c, 0, 0, 0);
}
__device__ __forceinline__ float gelu_f(float x) {
  return 0.5f * x * (1.0f + erff(x * 0.7071067811865475f));
}
// async global->LDS, 16B/lane; LDS dest = wave-uniform base + lane*16 (LINEAR — m104)
__device__ __forceinline__ void gl16(const u16* g, u16* l) {
  __builtin_amdgcn_global_load_lds((const __attribute__((address_space(1))) void*)g,
                                   (__attribute__((address_space(3))) void*)l, 16, 0, 0);
}
// counted vmcnt wait fused with raw barrier: single opaque asm so no memory op
// (ds_read / global_load_lds) can be scheduled across it (rule #18 class hazard).
template <int N>
__device__ __forceinline__ void wait_barrier() {
  asm volatile("s_waitcnt vmcnt(%0)\n\ts_barrier" ::"i"(N) : "memory");
}

// ---------------- generic complex GEMM (all-NT, 128x64 tile) ----------------
// C[m,n] = sum_k op(A)[m,k] op(B)[n,k]   (B is [N,K] row-major)
// CMODE 0 CMUL : Cr=ArBr-AiBi, Ci=ArBi+AiBr
// CMODE 1 CONJR: Cr=ArBr+AiBi (split) / ArBr (nonsplit real*real)
// CMODE 2 REALA: Cr=A*Br, Ci=A*Bi (A real bf16)
// CMODE 3 CONJA: Cr=ArBr+AiBi, Ci=ArBi-AiBr
// SPLIT=1: A (and optionally B) bf16x2 hi/lo pairs, 3-combo accumulate in one pass.
// DEEP=1 : R4 post-mortem showed the loop is LDS-BANDWIDTH-bound (48KB reads +
//          24KB DMA writes per K-step vs 155cyc of MFMA -> 24% ceiling = measured 23%).
//          All 4 waves read IDENTICAL B fragments, so B now comes DIRECT from global
//          (L1 broadcast within block, L2 across blocks) and LDS carries only A:
//          depth-3 staged, chunk-XOR swizzled (R3-verified 0 conflicts), counted vmcnt.
// DEEP=0 : verified single-buffered two-barrier loop with B in LDS (scores only:
//          K=64, 2 K-steps, write-bound).
struct GemmP {
  const u16 *Arh, *Aih, *Arl, *Ail;
  const u16 *Brh, *Bih, *Brl, *Bil;
  const float *biasr, *biasi;
  const float *Resr, *Resi;
  float *Cr32, *Ci32;
  u16 *Crh, *Cih, *Crl, *Cil;
  i64 sA1, sA2, sB1, sB2, sC1, sC2;
  int ZH;
  int M, N, K, lda, ldb, ldc;
  float alpha;
  int beta, wb32, ctrans, bias_mode, bias_period, gelu, splitB;
  float bias_scale;
};

template <int CMODE, int SPLIT, int DEEP>
__global__ __launch_bounds__(256, 2) void cgemm_kernel(GemmP p) {
  constexpr bool HAS_CI = (CMODE == 0 || CMODE == 2 || CMODE == 3);
  constexpr bool AI = (CMODE == 0 || CMODE == 3);
  constexpr bool BIc = (CMODE == 0 || CMODE == 2 || CMODE == 3);
  // DEEP buffers hold A ONLY. nonsplit: 8KB/comp; split: 4 comps = 16KB.
  constexpr int BUFU = SPLIT ? (DEEP ? 16384 : 24576) : (AI ? 8192 : 4096);
  constexpr int NBUF = DEEP ? 3 : 1;
  __shared__ u16 smem[BUFU * NBUF];
  constexpr int LPSA = SPLIT ? 8 : (AI ? 4 : 2);  // gl16 issues per A-stage (DEEP)

  const int tid = threadIdx.x, lane = tid & 63, wave = tid >> 6;
  const int lrow = lane & 15, quad = lane >> 4;
  const int m0 = blockIdx.y * 128, n0 = blockIdx.x * 64;
  const int z1 = blockIdx.z / p.ZH, z2 = blockIdx.z % p.ZH;
  const i64 zA = (i64)z1 * p.sA1 + (i64)z2 * p.sA2;
  const i64 zB = (i64)z1 * p.sB1 + (i64)z2 * p.sB2;
  const i64 zC = (i64)z1 * p.sC1 + (i64)z2 * p.sC2;
  const int l4 = lane >> 2;
  // DEEP: pre-swizzled global source chunk for the A stage (both-sides-or-neither,
  // m104/m231): LDS slot (row r, chunk c) holds logical chunk c ^ ((r>>1)&3).
  const int lc = DEEP ? ((((lane & 3) ^ ((lane >> 3) & 3))) << 3) : ((lane & 3) << 3);
  const i64 aoff0 = zA + (i64)(m0 + 32 * wave + l4) * p.lda + lc;
  const i64 aoff1 = aoff0 + (i64)16 * p.lda;
  const i64 boff = zB + (i64)(n0 + 16 * wave + l4) * p.ldb + lc;  // !DEEP staging only
  const int lA0 = (32 * wave) * 32, lA1 = lA0 + 512;
  const int lB0 = (16 * wave) * 32;
  const int cxw = ((lrow >> 1) & 3) << 3;  // read-side swizzle XOR (u16 units)

  // DEEP: direct-global B fragment row offsets (identical across the 4 waves -> L1)
  i64 bro[4];
#pragma unroll
  for (int j = 0; j < 4; ++j)
    bro[j] = zB + (i64)(n0 + j * 16 + lrow) * p.ldb + quad * 8;

  f32x4 accR[2][4], accI[2][4];
  const f32x4 z4 = {0.f, 0.f, 0.f, 0.f};
#pragma unroll
  for (int i = 0; i < 2; ++i)
#pragma unroll
    for (int j = 0; j < 4; ++j) { accR[i][j] = z4; accI[i][j] = z4; }

  const int ktn = p.K >> 5;

  if constexpr (SPLIT && !DEEP) {
    // ---- verified single-buffered two-barrier loop (scores path), B in LDS ----
    for (int kt = 0; kt < ktn; ++kt) {
      const i64 kc = (i64)(kt << 5);
      __syncthreads();  // all waves done reading previous tile
      gl16(p.Arh + aoff0 + kc, smem + lA0);
      gl16(p.Arh + aoff1 + kc, smem + lA1);
      gl16(p.Aih + aoff0 + kc, smem + 4096 + lA0);
      gl16(p.Aih + aoff1 + kc, smem + 4096 + lA1);
      gl16(p.Arl + aoff0 + kc, smem + 8192 + lA0);
      gl16(p.Arl + aoff1 + kc, smem + 8192 + lA1);
      gl16(p.Ail + aoff0 + kc, smem + 12288 + lA0);
      gl16(p.Ail + aoff1 + kc, smem + 12288 + lA1);
      gl16(p.Brh + boff + kc, smem + 16384 + lB0);
      gl16(p.Bih + boff + kc, smem + 18432 + lB0);
      if (p.splitB) {
        gl16(p.Brl + boff + kc, smem + 20480 + lB0);
        gl16(p.Bil + boff + kc, smem + 22528 + lB0);
      }
      __syncthreads();  // drains vmcnt -> DMA landed

      short8 bRh[4], bIh[4], bRl[4], bIl[4];
#pragma unroll
      for (int j = 0; j < 4; ++j) {
        const int off = (j * 16 + lrow) * 32 + quad * 8;
        bRh[j] = *(const short8*)&smem[16384 + off];
        bIh[j] = *(const short8*)&smem[18432 + off];
        if (p.splitB) {
          bRl[j] = *(const short8*)&smem[20480 + off];
          bIl[j] = *(const short8*)&smem[22528 + off];
        }
      }
#pragma unroll
      for (int i = 0; i < 2; ++i) {
        const int off = (wave * 32 + i * 16 + lrow) * 32 + quad * 8;
        short8 aRh = *(const short8*)&smem[off];
        short8 aIh = *(const short8*)&smem[4096 + off];
        short8 aRl = *(const short8*)&smem[8192 + off];
        short8 aIl = *(const short8*)&smem[12288 + off];
        if constexpr (CMODE == 0) {
          short8 nIh = neg8(aIh), nIl = neg8(aIl);
#pragma unroll
          for (int j = 0; j < 4; ++j) {
            accR[i][j] = mfma16(aRh, bRh[j], accR[i][j]);
            accR[i][j] = mfma16(nIh, bIh[j], accR[i][j]);
            accI[i][j] = mfma16(aRh, bIh[j], accI[i][j]);
            accI[i][j] = mfma16(aIh, bRh[j], accI[i][j]);
            accR[i][j] = mfma16(aRl, bRh[j], accR[i][j]);
            accR[i][j] = mfma16(nIl, bIh[j], accR[i][j]);
            accI[i][j] = mfma16(aRl, bIh[j], accI[i][j]);
            accI[i][j] = mfma16(aIl, bRh[j], accI[i][j]);
            if (p.splitB) {
              accR[i][j] = mfma16(aRh, bRl[j], accR[i][j]);
              accR[i][j] = mfma16(nIh, bIl[j], accR[i][j]);
              accI[i][j] = mfma16(aRh, bIl[j], accI[i][j]);
              accI[i][j] = mfma16(aIh, bRl[j], accI[i][j]);
            }
          }
        } else {  // CONJR split: Re(Q conj(K)) 3-combo
#pragma unroll
          for (int j = 0; j < 4; ++j) {
            accR[i][j] = mfma16(aRh, bRh[j], accR[i][j]);
            accR[i][j] = mfma16(aIh, bIh[j], accR[i][j]);
            accR[i][j] = mfma16(aRl, bRh[j], accR[i][j]);
            accR[i][j] = mfma16(aIl, bIh[j], accR[i][j]);
            accR[i][j] = mfma16(aRh, bRl[j], accR[i][j]);
            accR[i][j] = mfma16(aIh, bIl[j], accR[i][j]);
          }
        }
      }
    }
  } else if constexpr (SPLIT && DEEP) {
    // ---- depth-3 A-only pipeline + direct-global B (4 comps) ----
    auto stageA = [&](int buf, i64 kc) {
      u16* s = smem + buf * 16384;
      gl16(p.Arh + aoff0 + kc, s + lA0);
      gl16(p.Arh + aoff1 + kc, s + lA1);
      gl16(p.Aih + aoff0 + kc, s + 4096 + lA0);
      gl16(p.Aih + aoff1 + kc, s + 4096 + lA1);
      gl16(p.Arl + aoff0 + kc, s + 8192 + lA0);
      gl16(p.Arl + aoff1 + kc, s + 8192 + lA1);
      gl16(p.Ail + aoff0 + kc, s + 12288 + lA0);
      gl16(p.Ail + aoff1 + kc, s + 12288 + lA1);
    };
    if (ktn > 0) stageA(0, 0);
    if (ktn > 1) stageA(1, 32);
    for (int kt = 0; kt < ktn; ++kt) {
      if (kt + 1 < ktn) wait_barrier<LPSA>(); else wait_barrier<0>();
      const i64 kc = (i64)(kt << 5);
      // B register loads FIRST (so the compiler's B-use waitcnt only leaves the
      // newest A-stage in flight), then issue next A-stage.
      short8 bRh[4], bIh[4], bRl[4], bIl[4];
#pragma unroll
      for (int j = 0; j < 4; ++j) {
        bRh[j] = *(const short8*)(p.Brh + bro[j] + kc);
        bIh[j] = *(const short8*)(p.Bih + bro[j] + kc);
        if (p.splitB) {
          bRl[j] = *(const short8*)(p.Brl + bro[j] + kc);
          bIl[j] = *(const short8*)(p.Bil + bro[j] + kc);
        }
      }
      if (kt + 2 < ktn) stageA((kt + 2) % 3, (i64)((kt + 2) << 5));
      const u16* sb = smem + (kt % 3) * 16384;
#pragma unroll
      for (int i = 0; i < 2; ++i) {
        const int off = (wave * 32 + i * 16 + lrow) * 32 + (quad * 8 ^ cxw);
        short8 aRh = *(const short8*)&sb[off];
        short8 aIh = *(const short8*)&sb[4096 + off];
        short8 aRl = *(const short8*)&sb[8192 + off];
        short8 aIl = *(const short8*)&sb[12288 + off];
        if constexpr (CMODE == 0) {
          short8 nIh = neg8(aIh), nIl = neg8(aIl);
#pragma unroll
          for (int j = 0; j < 4; ++j) {
            accR[i][j] = mfma16(aRh, bRh[j], accR[i][j]);
            accR[i][j] = mfma16(nIh, bIh[j], accR[i][j]);
            accI[i][j] = mfma16(aRh, bIh[j], accI[i][j]);
            accI[i][j] = mfma16(aIh, bRh[j], accI[i][j]);
            accR[i][j] = mfma16(aRl, bRh[j], accR[i][j]);
            accR[i][j] = mfma16(nIl, bIh[j], accR[i][j]);
            accI[i][j] = mfma16(aRl, bIh[j], accI[i][j]);
            accI[i][j] = mfma16(aIl, bRh[j], accI[i][j]);
            if (p.splitB) {
              accR[i][j] = mfma16(aRh, bRl[j], accR[i][j]);
              accR[i][j] = mfma16(nIh, bIl[j], accR[i][j]);
              accI[i][j] = mfma16(aRh, bIl[j], accI[i][j]);
              accI[i][j] = mfma16(aIh, bRl[j], accI[i][j]);
            }
          }
        } else {  // CONJR split
#pragma unroll
          for (int j = 0; j < 4; ++j) {
            accR[i][j] = mfma16(aRh, bRh[j], accR[i][j]);
            accR[i][j] = mfma16(aIh, bIh[j], accR[i][j]);
            accR[i][j] = mfma16(aRl, bRh[j], accR[i][j]);
            accR[i][j] = mfma16(aIl, bIh[j], accR[i][j]);
            accR[i][j] = mfma16(aRh, bRl[j], accR[i][j]);
            accR[i][j] = mfma16(aIh, bIl[j], accR[i][j]);
          }
        }
      }
    }
  } else {
    // ---- depth-3 A-only pipeline + direct-global B (1-2 comps) ----
    auto stageA = [&](int buf, i64 kc) {
      u16* s = smem + buf * BUFU;
      gl16(p.Arh + aoff0 + kc, s + lA0);
      gl16(p.Arh + aoff1 + kc, s + lA1);
      if constexpr (AI) {
        gl16(p.Aih + aoff0 + kc, s + 4096 + lA0);
        gl16(p.Aih + aoff1 + kc, s + 4096 + lA1);
      }
    };
    if (ktn > 0) stageA(0, 0);
    if (ktn > 1) stageA(1, 32);
    for (int kt = 0; kt < ktn; ++kt) {
      if (kt + 1 < ktn) wait_barrier<LPSA>(); else wait_barrier<0>();
      const i64 kc = (i64)(kt << 5);
      short8 bR[4], bI[4];
#pragma unroll
      for (int j = 0; j < 4; ++j) {
        bR[j] = *(const short8*)(p.Brh + bro[j] + kc);
        if constexpr (BIc) bI[j] = *(const short8*)(p.Bih + bro[j] + kc);
      }
      if (kt + 2 < ktn) stageA((kt + 2) % 3, (i64)((kt + 2) << 5));
      const u16* sb = smem + (kt % 3) * BUFU;
#pragma unroll
      for (int i = 0; i < 2; ++i) {
        const int off = (wave * 32 + i * 16 + lrow) * 32 + (quad * 8 ^ cxw);
        short8 aR = *(const short8*)&sb[off];
        if constexpr (CMODE == 0) {
          short8 aI = *(const short8*)&sb[4096 + off];
          short8 nI = neg8(aI);
#pragma unroll
          for (int j = 0; j < 4; ++j) {
            accR[i][j] = mfma16(aR, bR[j], accR[i][j]);
            accR[i][j] = mfma16(nI, bI[j], accR[i][j]);
            accI[i][j] = mfma16(aR, bI[j], accI[i][j]);
            accI[i][j] = mfma16(aI, bR[j], accI[i][j]);
          }
        } else if constexpr (CMODE == 1) {  // real*real
#pragma unroll
          for (int j = 0; j < 4; ++j) accR[i][j] = mfma16(aR, bR[j], accR[i][j]);
        } else if constexpr (CMODE == 2) {  // A real, B complex
#pragma unroll
          for (int j = 0; j < 4; ++j) {
            accR[i][j] = mfma16(aR, bR[j], accR[i][j]);
            accI[i][j] = mfma16(aR, bI[j], accI[i][j]);
          }
        } else {  // CONJA
          short8 aI = *(const short8*)&sb[4096 + off];
          short8 nI = neg8(aI);
#pragma unroll
          for (int j = 0; j < 4; ++j) {
            accR[i][j] = mfma16(aR, bR[j], accR[i][j]);
            accR[i][j] = mfma16(aI, bI[j], accR[i][j]);
            accI[i][j] = mfma16(aR, bI[j], accI[i][j]);
            accI[i][j] = mfma16(nI, bR[j], accI[i][j]);
          }
        }
      }
    }
  }

  // ---- epilogue ----
#pragma unroll
  for (int i = 0; i < 2; ++i) {
#pragma unroll
    for (int j = 0; j < 4; ++j) {
      const int gn = n0 + j * 16 + lrow;
#pragma unroll
      for (int r = 0; r < 4; ++r) {
        const int gm = m0 + wave * 32 + i * 16 + quad * 4 + r;
        const i64 idx = p.ctrans ? (zC + (i64)gn * p.ldc + gm) : (zC + (i64)gm * p.ldc + gn);
        float vr = accR[i][j][r] * p.alpha;
        float vi = 0.f;
        if (HAS_CI) vi = accI[i][j][r] * p.alpha;
        if (p.beta) {
          vr += p.Cr32[idx];
          if (HAS_CI && p.Ci32) vi += p.Ci32[idx];
        }
        if (p.bias_mode == 1) {
          vr += p.biasr[gn];
          if (HAS_CI) vi += p.biasi[gn];
        } else if (p.bias_mode == 2) {
          if ((gm % p.bias_period) == 0) {
            vr += p.biasr[gn] * p.bias_scale;
            if (HAS_CI) vi += p.biasi[gn] * p.bias_scale;
          }
        }
        if (p.Resr) vr += p.Resr[idx];
        if (HAS_CI && p.Resi) vi += p.Resi[idx];
        if (p.gelu) {
          vr = gelu_f(vr);
          if (HAS_CI) vi = gelu_f(vi);
        }
        if (p.wb32 && p.Cr32) p.Cr32[idx] = vr;
        if (p.wb32 && HAS_CI && p.Ci32) p.Ci32[idx] = vi;
        if (p.Crh) {
          const u16 hh = f2bf(vr);
          p.Crh[idx] = hh;
          if (p.Crl) p.Crl[idx] = f2bf(vr - bf2f(hh));
        }
        if (HAS_CI && p.Cih) {
          const u16 hh = f2bf(vi);
          p.Cih[idx] = hh;
          if (p.Cil) p.Cil[idx] = f2bf(vi - bf2f(hh));
        }
      }
    }
  }
}

// ---------------- pointwise kernels ----------------
struct CvtBatch {
  const float* src[12];
  u16* hi[12];
  u16* lo[12];
  i64 cum[13];
};
__global__ __launch_bounds__(256) void cvt_batch_kernel(CvtBatch b) {
  const i64 k = (i64)blockIdx.x * 1024 + (i64)threadIdx.x * 4;
  int s = 0;
  while (k >= b.cum[s + 1]) ++s;  // all segment sizes are multiples of 1024
  const i64 base = k - b.cum[s];
  float4 v = *(const float4*)(b.src[s] + base);
  u16* hp = b.hi[s];
  u16* lp = b.lo[s];
  ushort4 h, l;
  h.x = f2bf(v.x); l.x = f2bf(v.x - bf2f(h.x));
  h.y = f2bf(v.y); l.y = f2bf(v.y - bf2f(h.y));
  h.z = f2bf(v.z); l.z = f2bf(v.z - bf2f(h.z));
  h.w = f2bf(v.w); l.w = f2bf(v.w - bf2f(h.w));
  *(ushort4*)(hp + base) = h;
  if (lp) *(ushort4*)(lp + base) = l;
}

// standalone convert (used for Hm -> Xh AFTER scores region is dead — liveness invariant!)
__global__ __launch_bounds__(256) void cvt_split_kernel(const float* in, u16* hi, u16* lo,
                                                        i64 n, const float* scale_ptr) {
  const i64 base = (i64)blockIdx.x * 1024 + (i64)threadIdx.x * 4;
  const float s = scale_ptr ? *scale_ptr : 1.0f;
#pragma unroll
  for (int e = 0; e < 4; ++e) {
    const i64 k = base + e;
    if (k < n) {
      const float v = in[k] * s;
      const u16 h = f2bf(v);
      hi[k] = h;
      if (lo) lo[k] = f2bf(v - bf2f(h));
    }
  }
}

// x[b][j][d] fp32 -> xT[b][d][j] bf16 hi/lo  (32x32 LDS tile transpose)
__global__ __launch_bounds__(256) void trans_cvt_kernel(const float* in, u16* outh, u16* outl) {
  __shared__ float t[32][33];
  const int b = blockIdx.z;
  const int j0 = blockIdx.y * 32;
  const int d0 = blockIdx.x * 32;
  const int r = threadIdx.x >> 5, c = threadIdx.x & 31;
  const float* ip = in + (i64)b * 1048576;
#pragma unroll
  for (int it = 0; it < 4; ++it) t[r + it * 8][c] = ip[(i64)(j0 + r + it * 8) * 1024 + d0 + c];
  __syncthreads();
  u16* ohp = outh + (i64)b * 1048576;
  u16* olp = outl + (i64)b * 1048576;
#pragma unroll
  for (int it = 0; it < 4; ++it) {
    const float v = t[c][r + it * 8];
    const i64 o = (i64)(d0 + r + it * 8) * 1024 + j0 + c;
    const u16 h = f2bf(v);
    ohp[o] = h;
    olp[o] = f2bf(v - bf2f(h));
  }
}

__global__ __launch_bounds__(256) void gen_F_kernel(u16* Frh, u16* Frl, u16* Fih, u16* Fil) {
  const int idx = blockIdx.x * 256 + threadIdx.x;
  const int mm = idx >> 10, kk = idx & 1023;
  const int t = (mm * kk) & 1023;
  float sv, cv;
  sincosf((float)t * 6.135923151e-3f, &sv, &cv);  // 2*pi/1024
  const float fr = cv, fi = -sv;
  u16 h = f2bf(fr);
  Frh[idx] = h;
  Frl[idx] = f2bf(fr - bf2f(h));
  h = f2bf(fi);
  Fih[idx] = h;
  Fil[idx] = f2bf(fi - bf2f(h));
}

// U = expm(-iHdt) ~ (I - X^2/2) + i(-X), X=H dt (X^3/6 term ~1e-6 el, dropped)
__global__ __launch_bounds__(256) void assemble_U_kernel(const float* X2m, const float* Hm,
                                                         const float* dtp, u16* Urh, u16* Uih) {
  const int idx = blockIdx.x * 256 + threadIdx.x;
  const int i = idx >> 10, j = idx & 1023;
  const float dt = *dtp;
  const float ur = ((i == j) ? 1.0f : 0.0f) - 0.5f * X2m[idx];
  const float ui = -dt * Hm[idx];
  Urh[idx] = f2bf(ur);
  Uih[idx] = f2bf(ui);
}

// softmax over 1024 fp32, writes bf16 probs in-place at row start (row stride stays 4KB)
__global__ __launch_bounds__(256) void softmax_kernel(float* S) {
  float* row = S + (i64)blockIdx.x * 1024;
  const int t = threadIdx.x;
  float4 v = *(float4*)(row + t * 4);
  float m = fmaxf(fmaxf(v.x, v.y), fmaxf(v.z, v.w));
#pragma unroll
  for (int off = 32; off > 0; off >>= 1) m = fmaxf(m, __shfl_down(m, off));
  __shared__ float red[8];
  const int lane = t & 63, w = t >> 6;
  if (lane == 0) red[w] = m;
  __syncthreads();
  if (t == 0) red[4] = fmaxf(fmaxf(red[0], red[1]), fmaxf(red[2], red[3]));
  __syncthreads();
  m = red[4];
  v.x = expf(v.x - m);
  v.y = expf(v.y - m);
  v.z = expf(v.z - m);
  v.w = expf(v.w - m);
  float s = v.x + v.y + v.z + v.w;
#pragma unroll
  for (int off = 32; off > 0; off >>= 1) s += __shfl_down(s, off);
  if (lane == 0) red[w] = s;
  __syncthreads();
  if (t == 0) red[5] = red[0] + red[1] + red[2] + red[3];
  __syncthreads();
  const float inv = 1.0f / red[5];
  ushort4 o;
  o.x = f2bf(v.x * inv);
  o.y = f2bf(v.y * inv);
  o.z = f2bf(v.z * inv);
  o.w = f2bf(v.w * inv);
  *(ushort4*)((u16*)row + t * 4) = o;
}

// ---------------- host side ----------------
static void run_gemm(hipStream_t s, int cmode, int split, int deep, const GemmP& p, int Z) {
  dim3 g((unsigned)(p.N >> 6), (unsigned)(p.M >> 7), (unsigned)Z);
  dim3 b(256, 1, 1);
  if (split) {
    if (deep) hipLaunchKernelGGL(HIP_KERNEL_NAME(cgemm_kernel<0, 1, 1>), g, b, 0, s, p);
    else hipLaunchKernelGGL(HIP_KERNEL_NAME(cgemm_kernel<1, 1, 0>), g, b, 0, s, p);
  } else {
    if (cmode == 0) hipLaunchKernelGGL(HIP_KERNEL_NAME(cgemm_kernel<0, 0, 1>), g, b, 0, s, p);
    else if (cmode == 1) hipLaunchKernelGGL(HIP_KERNEL_NAME(cgemm_kernel<1, 0, 1>), g, b, 0, s, p);
    else if (cmode == 2) hipLaunchKernelGGL(HIP_KERNEL_NAME(cgemm_kernel<2, 0, 1>), g, b, 0, s, p);
    else hipLaunchKernelGGL(HIP_KERNEL_NAME(cgemm_kernel<3, 0, 1>), g, b, 0, s, p);
  }
}

extern "C" void kernel_launch(void* const* d_in, const int* in_sizes, int n_in, void* d_out,
                              int out_size, void* d_ws, size_t ws_size, hipStream_t stream) {
  (void)in_sizes; (void)n_in; (void)out_size; (void)ws_size;
  const float* x_real = (const float*)d_in[0];
  const float* x_imag = (const float*)d_in[1];
  const float* Wr_q = (const float*)d_in[2];
  const float* Wi_q = (const float*)d_in[3];
  const float* br_q = (const float*)d_in[4];
  const float* bi_q = (const float*)d_in[5];
  const float* Wr_k = (const float*)d_in[6];
  const float* Wi_k = (const float*)d_in[7];
  const float* br_k = (const float*)d_in[8];
  const float* bi_k = (const float*)d_in[9];
  const float* Wr_v = (const float*)d_in[10];
  const float* Wi_v = (const float*)d_in[11];
  const float* br_v = (const float*)d_in[12];
  const float* bi_v = (const float*)d_in[13];
  const float* Wr_o = (const float*)d_in[14];
  const float* Wi_o = (const float*)d_in[15];
  const float* br_o = (const float*)d_in[16];
  const float* bi_o = (const float*)d_in[17];
  const float* Wr_f1 = (const float*)d_in[18];
  const float* Wi_f1 = (const float*)d_in[19];
  const float* br_f1 = (const float*)d_in[20];
  const float* bi_f1 = (const float*)d_in[21];
  const float* Wr_f2 = (const float*)d_in[22];
  const float* Wi_f2 = (const float*)d_in[23];
  const float* br_f2 = (const float*)d_in[24];
  const float* bi_f2 = (const float*)d_in[25];
  const float* Hm = (const float*)d_in[26];
  const float* dtp = (const float*)d_in[27];

  const size_t MBy = 1ull << 20;
  char* W = (char*)d_ws;
  auto U16 = [&](size_t mb) { return (u16*)(W + mb * MBy); };
  auto F32p = [&](size_t mb) { return (float*)(W + mb * MBy); };

  // zone 1 [0,128MB): scores fp32 region, time-shared with transients.
  // LIVENESS INVARIANT: anything here that is READ after the scores GEMM must be
  // WRITTEN after PV (last scores reader). Xh/X2m/U obey this (written post-f2).
  float* scores = F32p(0);
  u16 *xT_rh = U16(0), *xT_ih = U16(4), *xT_rl = U16(8), *xT_il = U16(12);
  u16 *Wq_rh = U16(16), *Wq_ih = U16(18), *Wq_rl = U16(20), *Wq_il = U16(22);
  u16 *Wk_rh = U16(24), *Wk_ih = U16(26), *Wk_rl = U16(28), *Wk_il = U16(30);
  u16 *xf_rh = U16(32), *xf_ih = U16(36), *xf_rl = U16(40), *xf_il = U16(44);
  u16 *h_r = U16(64), *h_i = U16(80);
  u16 *x2_rh = U16(96), *x2_ih = U16(100), *x2_rl = U16(104), *x2_il = U16(108);
  u16* Xh = U16(112);
  float* X2m = F32p(114);
  u16 *Urh = U16(124), *Uih = U16(126);
  // zone 2 [128MB,256MB): persistent
  u16 *Wv_rh = U16(128), *Wv_ih = U16(130);
  u16 *Wo_rh = U16(132), *Wo_ih = U16(134);
  u16 *Wf1_rh = U16(136), *Wf1_ih = U16(144);
  u16 *Wf2_rh = U16(152), *Wf2_ih = U16(160);
  u16 *F_rh = U16(168), *F_ih = U16(170), *F_rl = U16(172), *F_il = U16(174);
  u16 *Qf_rh = U16(176), *Qf_ih = U16(180), *Qf_rl = U16(184), *Qf_il = U16(188);
  u16 *Kf_rh = U16(192), *Kf_ih = U16(196), *Kf_rl = U16(200), *Kf_il = U16(204);
  u16 *VfT_r = U16(208), *VfT_i = U16(212);  // [b][d][seq]
  u16 *ofT_r = U16(216), *ofT_i = U16(220);  // [b][d][seq]
  u16 *ot_r = U16(224), *ot_i = U16(228);    // [b*seq][d]
  float* x1_r = F32p(232);
  float* x1_i = F32p(240);
  u16 *x1h_r = U16(248), *x1h_i = U16(252);

  // ---- batched conversions (weights ONLY — Hm deferred past scores lifetime) ----
  {
    CvtBatch b{};
    const float* srcs[12] = {Wr_q, Wi_q, Wr_k, Wi_k, Wr_v, Wi_v, Wr_o, Wi_o,
                             Wr_f1, Wi_f1, Wr_f2, Wi_f2};
    u16* his[12] = {Wq_rh, Wq_ih, Wk_rh, Wk_ih, Wv_rh, Wv_ih, Wo_rh, Wo_ih,
                    Wf1_rh, Wf1_ih, Wf2_rh, Wf2_ih};
    u16* los[12] = {Wq_rl, Wq_il, Wk_rl, Wk_il, nullptr, nullptr, nullptr, nullptr,
                    nullptr, nullptr, nullptr, nullptr};
    const i64 sizes[12] = {1048576, 1048576, 1048576, 1048576, 1048576, 1048576, 1048576,
                           1048576, 4194304, 4194304, 4194304, 4194304};
    i64 c = 0;
    for (int i = 0; i < 12; ++i) {
      b.src[i] = srcs[i]; b.hi[i] = his[i]; b.lo[i] = los[i];
      b.cum[i] = c; c += sizes[i];
    }
    b.cum[12] = c;
    hipLaunchKernelGGL(cvt_batch_kernel, dim3((unsigned)(c / 1024)), dim3(256), 0, stream, b);
  }
  hipLaunchKernelGGL(trans_cvt_kernel, dim3(32, 32, 2), dim3(256), 0, stream, x_real, xT_rh, xT_rl);
  hipLaunchKernelGGL(trans_cvt_kernel, dim3(32, 32, 2), dim3(256), 0, stream, x_imag, xT_ih, xT_il);
  hipLaunchKernelGGL(gen_F_kernel, dim3(4096), dim3(256), 0, stream, F_rh, F_rl, F_ih, F_il);

  GemmP p;
  auto clearp = [&]() {
    p = GemmP{};
    p.alpha = 1.0f;
    p.ZH = 1;
  };

  // ---- DFT: xf[b] = F @ x[b], fused bf16x2 (A=F h/l, B=xT h/l) ----
  clearp();
  p.M = 1024; p.N = 1024; p.K = 1024; p.lda = 1024; p.ldb = 1024; p.ldc = 1024;
  p.sB1 = 1048576; p.sC1 = 1048576;
  p.Arh = F_rh; p.Aih = F_ih; p.Arl = F_rl; p.Ail = F_il;
  p.Brh = xT_rh; p.Bih = xT_ih; p.Brl = xT_rl; p.Bil = xT_il; p.splitB = 1;
  p.Crh = xf_rh; p.Cih = xf_ih; p.Crl = xf_rl; p.Cil = xf_il;
  run_gemm(stream, 0, 1, 1, p, 2);

  // ---- Q/K projections, fused bf16x2 ----
  auto proj = [&](const u16* Wrh, const u16* Wih, const u16* Wrl, const u16* Wil,
                  const float* br, const float* bi, u16* Orh, u16* Oih, u16* Orl, u16* Oil) {
    clearp();
    p.M = 2048; p.N = 1024; p.K = 1024; p.lda = 1024; p.ldb = 1024; p.ldc = 1024;
    p.Arh = xf_rh; p.Aih = xf_ih; p.Arl = xf_rl; p.Ail = xf_il;
    p.Brh = Wrh; p.Bih = Wih; p.Brl = Wrl; p.Bil = Wil; p.splitB = 1;
    p.bias_mode = 2; p.bias_period = 1024; p.bias_scale = 1024.0f;
    p.biasr = br; p.biasi = bi;
    p.Crh = Orh; p.Cih = Oih; p.Crl = Orl; p.Cil = Oil;
    run_gemm(stream, 0, 1, 1, p, 1);
  };
  proj(Wq_rh, Wq_ih, Wq_rl, Wq_il, br_q, bi_q, Qf_rh, Qf_ih, Qf_rl, Qf_il);
  proj(Wk_rh, Wk_ih, Wk_rl, Wk_il, br_k, bi_k, Kf_rh, Kf_ih, Kf_rl, Kf_il);

  // ---- V projection (plain), TRANSPOSED output VfT[b][d][seq] ----
  clearp();
  p.M = 1024; p.N = 1024; p.K = 1024; p.lda = 1024; p.ldb = 1024; p.ldc = 1024;
  p.sA1 = 1048576; p.sC1 = 1048576;
  p.Arh = xf_rh; p.Aih = xf_ih; p.Brh = Wv_rh; p.Bih = Wv_ih;
  p.bias_mode = 2; p.bias_period = 1024; p.bias_scale = 1024.0f;
  p.biasr = br_v; p.biasi = bi_v;
  p.ctrans = 1;
  p.Crh = VfT_r; p.Cih = VfT_i;
  run_gemm(stream, 0, 0, 1, p, 2);

  // ---- scores = 0.125 * Re(Qf conj(Kf)^T) per head, fused bf16x2 ----
  clearp();
  p.M = 1024; p.N = 1024; p.K = 64; p.lda = 1024; p.ldb = 1024; p.ldc = 1024;
  p.ZH = 16;
  p.sA1 = 1048576; p.sA2 = 64; p.sB1 = 1048576; p.sB2 = 64;
  p.sC1 = 16ll * 1048576; p.sC2 = 1048576;
  p.alpha = 0.125f;
  p.Arh = Qf_rh; p.Aih = Qf_ih; p.Arl = Qf_rl; p.Ail = Qf_il;
  p.Brh = Kf_rh; p.Bih = Kf_ih; p.Brl = Kf_rl; p.Bil = Kf_il; p.splitB = 1;
  p.Cr32 = scores; p.wb32 = 1;
  run_gemm(stream, 1, 1, 0, p, 32);

  hipLaunchKernelGGL(softmax_kernel, dim3(32768), dim3(256), 0, stream, scores);

  // ---- PV: out_f = P @ Vf, P bf16 in-place (lda u16 = 2048), out transposed ofT ----
  clearp();
  p.M = 1024; p.N = 64; p.K = 1024; p.lda = 2048; p.ldb = 1024; p.ldc = 1024;
  p.ZH = 16;
  p.sA1 = 16ll * 2097152; p.sA2 = 2097152;
  p.sB1 = 1048576; p.sB2 = 65536;
  p.sC1 = 1048576; p.sC2 = 65536;
  p.ctrans = 1;
  p.Arh = (const u16*)scores; p.Brh = VfT_r; p.Bih = VfT_i;
  p.Crh = ofT_r; p.Cih = ofT_i;
  run_gemm(stream, 2, 0, 1, p, 32);

  // ---- IDFT: ot[b] = (1/N) conj(F) @ of[b] ----
  clearp();
  p.M = 1024; p.N = 1024; p.K = 1024; p.lda = 1024; p.ldb = 1024; p.ldc = 1024;
  p.sB1 = 1048576; p.sC1 = 1048576;
  p.alpha = 1.0f / 1024.0f;
  p.Arh = F_rh; p.Aih = F_ih; p.Brh = ofT_r; p.Bih = ofT_i;
  p.Crh = ot_r; p.Cih = ot_i;
  run_gemm(stream, 3, 0, 1, p, 2);

  // ---- x1 = x + ot @ Wo^T + b_o ----
  clearp();
  p.M = 2048; p.N = 1024; p.K = 1024; p.lda = 1024; p.ldb = 1024; p.ldc = 1024;
  p.Arh = ot_r; p.Aih = ot_i; p.Brh = Wo_rh; p.Bih = Wo_ih;
  p.bias_mode = 1; p.biasr = br_o; p.biasi = bi_o;
  p.Resr = x_real; p.Resi = x_imag;
  p.Cr32 = x1_r; p.Ci32 = x1_i; p.wb32 = 1; p.Crh = x1h_r; p.Cih = x1h_i;
  run_gemm(stream, 0, 0, 1, p, 1);

  // ---- h = gelu(x1 @ Wf1^T + b_f1) ----
  clearp();
  p.M = 2048; p.N = 4096; p.K = 1024; p.lda = 1024; p.ldb = 1024; p.ldc = 4096;
  p.Arh = x1h_r; p.Aih = x1h_i; p.Brh = Wf1_rh; p.Bih = Wf1_ih;
  p.bias_mode = 1; p.biasr = br_f1; p.biasi = bi_f1;
  p.gelu = 1;
  p.Crh = h_r; p.Cih = h_i;
  run_gemm(stream, 0, 0, 1, p, 1);

  // ---- x2 = x1 + h @ Wf2^T + b_f2 (emit x2 hi/lo) ----
  clearp();
  p.M = 2048; p.N = 1024; p.K = 4096; p.lda = 4096; p.ldb = 4096; p.ldc = 1024;
  p.Arh = h_r; p.Aih = h_i; p.Brh = Wf2_rh; p.Bih = Wf2_ih;
  p.bias_mode = 1; p.biasr = br_f2; p.biasi = bi_f2;
  p.Resr = x1_r; p.Resi = x1_i;
  p.Crh = x2_rh; p.Cih = x2_ih; p.Crl = x2_rl; p.Cil = x2_il;
  run_gemm(stream, 0, 0, 1, p, 1);

  // ---- Xh = bf16(H*dt) — NOW safe: scores region dead (PV was last reader) ----
  hipLaunchKernelGGL(cvt_split_kernel, dim3(1024), dim3(256), 0, stream, Hm, Xh,
                     (u16*)nullptr, (i64)1048576, dtp);

  // ---- X2 = X @ X (X symmetric -> NT) ----
  clearp();
  p.M = 1024; p.N = 1024; p.K = 1024; p.lda = 1024; p.ldb = 1024; p.ldc = 1024;
  p.Arh = Xh; p.Brh = Xh;
  p.Cr32 = X2m; p.wb32 = 1;
  run_gemm(stream, 1, 0, 1, p, 1);
  hipLaunchKernelGGL(assemble_U_kernel, dim3(4096), dim3(256), 0, stream, X2m, Hm, dtp, Urh, Uih);

  // ---- out = x2 @ U (U symmetric -> NT), fused split-A single pass ----
  float* out_r = (float*)d_out;
  float* out_i = out_r + 2097152;
  clearp();
  p.M = 2048; p.N = 1024; p.K = 1024; p.lda = 1024; p.ldb = 1024; p.ldc = 1024;
  p.Arh = x2_rh; p.Aih = x2_ih; p.Arl = x2_rl; p.Ail = x2_il;
  p.Brh = Urh; p.Bih = Uih; p.splitB = 0;
  p.Cr32 = out_r; p.Ci32 = out_i; p.wb32 = 1;
  run_gemm(stream, 0, 1, 1, p, 1);
}

// Round 6
// 1314.809 us; speedup vs baseline: 1.1113x; 1.1113x over previous
//
#include <hip/hip_runtime.h>
#include <cstdint>
#include <cstddef>

typedef unsigned int u32;
typedef unsigned short u16;
typedef long long i64;

typedef __attribute__((ext_vector_type(8))) short short8;
typedef __attribute__((ext_vector_type(4))) float f32x4;
typedef __attribute__((ext_vector_type(4))) int i32x4;

// ---------------- device helpers ----------------
__device__ __forceinline__ u16 f2bf(float f) {
  u32 u = __float_as_uint(f);
  u = (u + 0x7FFFu + ((u >> 16) & 1u)) >> 16;  // RNE
  return (u16)u;
}
__device__ __forceinline__ float bf2f(u16 h) { return __uint_as_float(((u32)h) << 16); }

__device__ __forceinline__ short8 neg8(short8 v) {
  i32x4 u = __builtin_bit_cast(i32x4, v);
  u = u ^ (int)0x80008000u;
  return __builtin_bit_cast(short8, u);
}
__device__ __forceinline__ f32x4 mfma16(short8 a, short8 b, f32x4 c) {
  return __builtin_amdgcn_mfma_f32_16x16x32_bf16(a, b, c, 0, 0, 0);
}
__device__ __forceinline__ float gelu_f(float x) {
  return 0.5f * x * (1.0f + erff(x * 0.7071067811865475f));
}
// async global->LDS, 16B/lane; LDS dest = wave-uniform base + lane*16 (LINEAR — m104)
__device__ __forceinline__ void gl16(const u16* g, u16* l) {
  __builtin_amdgcn_global_load_lds((const __attribute__((address_space(1))) void*)g,
                                   (__attribute__((address_space(3))) void*)l, 16, 0, 0);
}
// counted vmcnt wait fused with raw barrier: single opaque asm so no memory op
// (ds_read / global_load_lds / global_load) can be scheduled across it (rule #18).
template <int N>
__device__ __forceinline__ void wait_barrier() {
  asm volatile("s_waitcnt vmcnt(%0)\n\ts_barrier" ::"i"(N) : "memory");
}

// ---------------- generic complex GEMM (all-NT, 128x64 tile) ----------------
// C[m,n] = sum_k op(A)[m,k] op(B)[n,k]   (B is [N,K] row-major)
// CMODE 0 CMUL : Cr=ArBr-AiBi, Ci=ArBi+AiBr
// CMODE 1 CONJR: Cr=ArBr+AiBi (split) / ArBr (nonsplit real*real)
// CMODE 2 REALA: Cr=A*Br, Ci=A*Bi (A real bf16)
// CMODE 3 CONJA: Cr=ArBr+AiBi, Ci=ArBi-AiBr
// SPLIT=1 DEEP=1: R4-VERIFIED depth-3 A+B-in-LDS pipeline (118us, 0 conflicts).
// SPLIT=0 DEEP=1: depth-3 A-in-LDS pipeline + B REGISTER-PREFETCHED ONE ITERATION
//   AHEAD from global (R5 post-mortem: just-in-time direct B serialized L2 latency
//   every K-step -> 2x regression; prefetch distance 1 hides it while still cutting
//   LDS traffic 72->32 KB per K-step).
// SPLIT=1 DEEP=0: verified single-buffered two-barrier loop (scores only).
struct GemmP {
  const u16 *Arh, *Aih, *Arl, *Ail;
  const u16 *Brh, *Bih, *Brl, *Bil;
  const float *biasr, *biasi;
  const float *Resr, *Resi;
  float *Cr32, *Ci32;
  u16 *Crh, *Cih, *Crl, *Cil;
  i64 sA1, sA2, sB1, sB2, sC1, sC2;
  int ZH;
  int M, N, K, lda, ldb, ldc;
  float alpha;
  int beta, wb32, ctrans, bias_mode, bias_period, gelu, splitB;
  float bias_scale;
};

template <int CMODE, int SPLIT, int DEEP>
__global__ __launch_bounds__(256, 2) void cgemm_kernel(GemmP p) {
  constexpr bool HAS_CI = (CMODE == 0 || CMODE == 2 || CMODE == 3);
  constexpr bool AI = (CMODE == 0 || CMODE == 3);
  constexpr bool BIc = (CMODE == 0 || CMODE == 2 || CMODE == 3);
  // split: full A+B tile (48KB). nonsplit DEEP: A only (8 or 16KB).
  constexpr int BUFU = SPLIT ? 24576 : (AI ? 8192 : 4096);
  constexpr int NBUF = DEEP ? 3 : 1;
  __shared__ u16 smem[BUFU * NBUF];
  constexpr int LPSA = AI ? 4 : 2;     // gl16 per A-stage (nonsplit DEEP)
  constexpr int NB = BIc ? 8 : 4;      // B register loads per iteration (nonsplit DEEP)

  const int tid = threadIdx.x, lane = tid & 63, wave = tid >> 6;
  const int lrow = lane & 15, quad = lane >> 4;
  const int m0 = blockIdx.y * 128, n0 = blockIdx.x * 64;
  const int z1 = blockIdx.z / p.ZH, z2 = blockIdx.z % p.ZH;
  const i64 zA = (i64)z1 * p.sA1 + (i64)z2 * p.sA2;
  const i64 zB = (i64)z1 * p.sB1 + (i64)z2 * p.sB2;
  const i64 zC = (i64)z1 * p.sC1 + (i64)z2 * p.sC2;
  const int l4 = lane >> 2;
  // DEEP: pre-swizzled global source chunk for LDS staging (both-sides-or-neither,
  // m104/m231): LDS slot (row r, chunk c) holds logical chunk c ^ ((r>>1)&3).
  const int lc = DEEP ? ((((lane & 3) ^ ((lane >> 3) & 3))) << 3) : ((lane & 3) << 3);
  const i64 aoff0 = zA + (i64)(m0 + 32 * wave + l4) * p.lda + lc;
  const i64 aoff1 = aoff0 + (i64)16 * p.lda;
  const i64 boff = zB + (i64)(n0 + 16 * wave + l4) * p.ldb + lc;  // LDS-staged B paths
  const int lA0 = (32 * wave) * 32, lA1 = lA0 + 512;
  const int lB0 = (16 * wave) * 32;
  const int cxw = ((lrow >> 1) & 3) << 3;  // read-side swizzle XOR (u16 units)

  // nonsplit DEEP: direct-global B fragment row offsets (no swizzle — B skips LDS)
  i64 bro[4];
#pragma unroll
  for (int j = 0; j < 4; ++j)
    bro[j] = zB + (i64)(n0 + j * 16 + lrow) * p.ldb + quad * 8;

  f32x4 accR[2][4], accI[2][4];
  const f32x4 z4 = {0.f, 0.f, 0.f, 0.f};
#pragma unroll
  for (int i = 0; i < 2; ++i)
#pragma unroll
    for (int j = 0; j < 4; ++j) { accR[i][j] = z4; accI[i][j] = z4; }

  const int ktn = p.K >> 5;

  if constexpr (SPLIT && !DEEP) {
    // ---- verified single-buffered two-barrier loop (scores path), B in LDS ----
    for (int kt = 0; kt < ktn; ++kt) {
      const i64 kc = (i64)(kt << 5);
      __syncthreads();  // all waves done reading previous tile
      gl16(p.Arh + aoff0 + kc, smem + lA0);
      gl16(p.Arh + aoff1 + kc, smem + lA1);
      gl16(p.Aih + aoff0 + kc, smem + 4096 + lA0);
      gl16(p.Aih + aoff1 + kc, smem + 4096 + lA1);
      gl16(p.Arl + aoff0 + kc, smem + 8192 + lA0);
      gl16(p.Arl + aoff1 + kc, smem + 8192 + lA1);
      gl16(p.Ail + aoff0 + kc, smem + 12288 + lA0);
      gl16(p.Ail + aoff1 + kc, smem + 12288 + lA1);
      gl16(p.Brh + boff + kc, smem + 16384 + lB0);
      gl16(p.Bih + boff + kc, smem + 18432 + lB0);
      if (p.splitB) {
        gl16(p.Brl + boff + kc, smem + 20480 + lB0);
        gl16(p.Bil + boff + kc, smem + 22528 + lB0);
      }
      __syncthreads();  // drains vmcnt -> DMA landed

      short8 bRh[4], bIh[4], bRl[4], bIl[4];
#pragma unroll
      for (int j = 0; j < 4; ++j) {
        const int off = (j * 16 + lrow) * 32 + quad * 8;
        bRh[j] = *(const short8*)&smem[16384 + off];
        bIh[j] = *(const short8*)&smem[18432 + off];
        if (p.splitB) {
          bRl[j] = *(const short8*)&smem[20480 + off];
          bIl[j] = *(const short8*)&smem[22528 + off];
        }
      }
#pragma unroll
      for (int i = 0; i < 2; ++i) {
        const int off = (wave * 32 + i * 16 + lrow) * 32 + quad * 8;
        short8 aRh = *(const short8*)&smem[off];
        short8 aIh = *(const short8*)&smem[4096 + off];
        short8 aRl = *(const short8*)&smem[8192 + off];
        short8 aIl = *(const short8*)&smem[12288 + off];
        if constexpr (CMODE == 0) {
          short8 nIh = neg8(aIh), nIl = neg8(aIl);
#pragma unroll
          for (int j = 0; j < 4; ++j) {
            accR[i][j] = mfma16(aRh, bRh[j], accR[i][j]);
            accR[i][j] = mfma16(nIh, bIh[j], accR[i][j]);
            accI[i][j] = mfma16(aRh, bIh[j], accI[i][j]);
            accI[i][j] = mfma16(aIh, bRh[j], accI[i][j]);
            accR[i][j] = mfma16(aRl, bRh[j], accR[i][j]);
            accR[i][j] = mfma16(nIl, bIh[j], accR[i][j]);
            accI[i][j] = mfma16(aRl, bIh[j], accI[i][j]);
            accI[i][j] = mfma16(aIl, bRh[j], accI[i][j]);
            if (p.splitB) {
              accR[i][j] = mfma16(aRh, bRl[j], accR[i][j]);
              accR[i][j] = mfma16(nIh, bIl[j], accR[i][j]);
              accI[i][j] = mfma16(aRh, bIl[j], accI[i][j]);
              accI[i][j] = mfma16(aIh, bRl[j], accI[i][j]);
            }
          }
        } else {  // CONJR split: Re(Q conj(K)) 3-combo
#pragma unroll
          for (int j = 0; j < 4; ++j) {
            accR[i][j] = mfma16(aRh, bRh[j], accR[i][j]);
            accR[i][j] = mfma16(aIh, bIh[j], accR[i][j]);
            accR[i][j] = mfma16(aRl, bRh[j], accR[i][j]);
            accR[i][j] = mfma16(aIl, bIh[j], accR[i][j]);
            accR[i][j] = mfma16(aRh, bRl[j], accR[i][j]);
            accR[i][j] = mfma16(aIh, bIl[j], accR[i][j]);
          }
        }
      }
    }
  } else if constexpr (SPLIT && DEEP) {
    // ---- R4-VERIFIED depth-3 split pipeline: A+B in LDS, buffers at buf*24576 ----
    auto stageS = [&](int buf, i64 kc) {
      u16* s = smem + buf * 24576;
      gl16(p.Arh + aoff0 + kc, s + lA0);
      gl16(p.Arh + aoff1 + kc, s + lA1);
      gl16(p.Aih + aoff0 + kc, s + 4096 + lA0);
      gl16(p.Aih + aoff1 + kc, s + 4096 + lA1);
      gl16(p.Arl + aoff0 + kc, s + 8192 + lA0);
      gl16(p.Arl + aoff1 + kc, s + 8192 + lA1);
      gl16(p.Ail + aoff0 + kc, s + 12288 + lA0);
      gl16(p.Ail + aoff1 + kc, s + 12288 + lA1);
      gl16(p.Brh + boff + kc, s + 16384 + lB0);
      gl16(p.Bih + boff + kc, s + 18432 + lB0);
      if (p.splitB) {
        gl16(p.Brl + boff + kc, s + 20480 + lB0);
        gl16(p.Bil + boff + kc, s + 22528 + lB0);
      }
    };
    if (ktn > 0) stageS(0, 0);
    if (ktn > 1) stageS(1, 32);
    for (int kt = 0; kt < ktn; ++kt) {
      // leave tile kt+1's stage in flight; guarantee tile kt landed + compute(kt-1) done
      if (kt + 1 < ktn) {
        if (p.splitB) wait_barrier<12>(); else wait_barrier<10>();
      } else {
        wait_barrier<0>();
      }
      if (kt + 2 < ktn) stageS((kt + 2) % 3, (i64)((kt + 2) << 5));  // overwrites buf[(kt-1)%3]
      const u16* sb = smem + (kt % 3) * 24576;

      short8 bRh[4], bIh[4], bRl[4], bIl[4];
#pragma unroll
      for (int j = 0; j < 4; ++j) {
        const int off = (j * 16 + lrow) * 32 + (quad * 8 ^ cxw);
        bRh[j] = *(const short8*)&sb[16384 + off];
        bIh[j] = *(const short8*)&sb[18432 + off];
        if (p.splitB) {
          bRl[j] = *(const short8*)&sb[20480 + off];
          bIl[j] = *(const short8*)&sb[22528 + off];
        }
      }
#pragma unroll
      for (int i = 0; i < 2; ++i) {
        const int off = (wave * 32 + i * 16 + lrow) * 32 + (quad * 8 ^ cxw);
        short8 aRh = *(const short8*)&sb[off];
        short8 aIh = *(const short8*)&sb[4096 + off];
        short8 aRl = *(const short8*)&sb[8192 + off];
        short8 aIl = *(const short8*)&sb[12288 + off];
        if constexpr (CMODE == 0) {
          short8 nIh = neg8(aIh), nIl = neg8(aIl);
#pragma unroll
          for (int j = 0; j < 4; ++j) {
            accR[i][j] = mfma16(aRh, bRh[j], accR[i][j]);
            accR[i][j] = mfma16(nIh, bIh[j], accR[i][j]);
            accI[i][j] = mfma16(aRh, bIh[j], accI[i][j]);
            accI[i][j] = mfma16(aIh, bRh[j], accI[i][j]);
            accR[i][j] = mfma16(aRl, bRh[j], accR[i][j]);
            accR[i][j] = mfma16(nIl, bIh[j], accR[i][j]);
            accI[i][j] = mfma16(aRl, bIh[j], accI[i][j]);
            accI[i][j] = mfma16(aIl, bRh[j], accI[i][j]);
            if (p.splitB) {
              accR[i][j] = mfma16(aRh, bRl[j], accR[i][j]);
              accR[i][j] = mfma16(nIh, bIl[j], accR[i][j]);
              accI[i][j] = mfma16(aRh, bIl[j], accI[i][j]);
              accI[i][j] = mfma16(aIh, bRl[j], accI[i][j]);
            }
          }
        } else {  // CONJR split
#pragma unroll
          for (int j = 0; j < 4; ++j) {
            accR[i][j] = mfma16(aRh, bRh[j], accR[i][j]);
            accR[i][j] = mfma16(aIh, bIh[j], accR[i][j]);
            accR[i][j] = mfma16(aRl, bRh[j], accR[i][j]);
            accR[i][j] = mfma16(aIl, bIh[j], accR[i][j]);
            accR[i][j] = mfma16(aRh, bRl[j], accR[i][j]);
            accR[i][j] = mfma16(aIh, bIl[j], accR[i][j]);
          }
        }
      }
    }
  } else {
    // ---- depth-3 A-only LDS pipeline + B register-prefetched 1 iteration ahead ----
    auto stageA = [&](int buf, i64 kc) {
      u16* s = smem + buf * BUFU;
      gl16(p.Arh + aoff0 + kc, s + lA0);
      gl16(p.Arh + aoff1 + kc, s + lA1);
      if constexpr (AI) {
        gl16(p.Aih + aoff0 + kc, s + 4096 + lA0);
        gl16(p.Aih + aoff1 + kc, s + 4096 + lA1);
      }
    };
    short8 bCurR[4], bCurI[4], bNxtR[4], bNxtI[4];
    auto loadB = [&](short8* br, short8* bi, i64 kc) {
#pragma unroll
      for (int j = 0; j < 4; ++j) {
        br[j] = *(const short8*)(p.Brh + bro[j] + kc);
        if constexpr (BIc) bi[j] = *(const short8*)(p.Bih + bro[j] + kc);
      }
    };
    if (ktn > 0) stageA(0, 0);
    if (ktn > 1) stageA(1, 32);
    if (ktn > 0) loadB(bCurR, bCurI, 0);
#pragma unroll 2
    for (int kt = 0; kt < ktn; ++kt) {
      // Ensure A(kt) landed and all waves finished reading the buffer being
      // recycled. In flight (allowed): bNxt(kt)=bCur [NB] + stageA(kt+1) [LPSA].
      if (kt + 1 < ktn) wait_barrier<NB + LPSA>(); else wait_barrier<NB>();
      // issue next-tile B loads BEFORE next-next A stage (older -> retires first;
      // bCur's compiler waitcnt then tolerates 2*LPSA+NB newer ops = 1 full iter)
      if (kt + 1 < ktn) loadB(bNxtR, bNxtI, (i64)((kt + 1) << 5));
      if (kt + 2 < ktn) stageA((kt + 2) % 3, (i64)((kt + 2) << 5));
      const u16* sb = smem + (kt % 3) * BUFU;
#pragma unroll
      for (int i = 0; i < 2; ++i) {
        const int off = (wave * 32 + i * 16 + lrow) * 32 + (quad * 8 ^ cxw);
        short8 aR = *(const short8*)&sb[off];
        if constexpr (CMODE == 0) {
          short8 aI = *(const short8*)&sb[4096 + off];
          short8 nI = neg8(aI);
#pragma unroll
          for (int j = 0; j < 4; ++j) {
            accR[i][j] = mfma16(aR, bCurR[j], accR[i][j]);
            accR[i][j] = mfma16(nI, bCurI[j], accR[i][j]);
            accI[i][j] = mfma16(aR, bCurI[j], accI[i][j]);
            accI[i][j] = mfma16(aI, bCurR[j], accI[i][j]);
          }
        } else if constexpr (CMODE == 1) {  // real*real
#pragma unroll
          for (int j = 0; j < 4; ++j) accR[i][j] = mfma16(aR, bCurR[j], accR[i][j]);
        } else if constexpr (CMODE == 2) {  // A real, B complex
#pragma unroll
          for (int j = 0; j < 4; ++j) {
            accR[i][j] = mfma16(aR, bCurR[j], accR[i][j]);
            accI[i][j] = mfma16(aR, bCurI[j], accI[i][j]);
          }
        } else {  // CONJA
          short8 aI = *(const short8*)&sb[4096 + off];
          short8 nI = neg8(aI);
#pragma unroll
          for (int j = 0; j < 4; ++j) {
            accR[i][j] = mfma16(aR, bCurR[j], accR[i][j]);
            accR[i][j] = mfma16(aI, bCurI[j], accR[i][j]);
            accI[i][j] = mfma16(aR, bCurI[j], accI[i][j]);
            accI[i][j] = mfma16(nI, bCurR[j], accI[i][j]);
          }
        }
      }
      // rotate prefetched B into place (copy-prop eliminates under unroll)
#pragma unroll
      for (int j = 0; j < 4; ++j) {
        bCurR[j] = bNxtR[j];
        if constexpr (BIc) bCurI[j] = bNxtI[j];
      }
    }
  }

  // ---- epilogue ----
#pragma unroll
  for (int i = 0; i < 2; ++i) {
#pragma unroll
    for (int j = 0; j < 4; ++j) {
      const int gn = n0 + j * 16 + lrow;
#pragma unroll
      for (int r = 0; r < 4; ++r) {
        const int gm = m0 + wave * 32 + i * 16 + quad * 4 + r;
        const i64 idx = p.ctrans ? (zC + (i64)gn * p.ldc + gm) : (zC + (i64)gm * p.ldc + gn);
        float vr = accR[i][j][r] * p.alpha;
        float vi = 0.f;
        if (HAS_CI) vi = accI[i][j][r] * p.alpha;
        if (p.beta) {
          vr += p.Cr32[idx];
          if (HAS_CI && p.Ci32) vi += p.Ci32[idx];
        }
        if (p.bias_mode == 1) {
          vr += p.biasr[gn];
          if (HAS_CI) vi += p.biasi[gn];
        } else if (p.bias_mode == 2) {
          if ((gm % p.bias_period) == 0) {
            vr += p.biasr[gn] * p.bias_scale;
            if (HAS_CI) vi += p.biasi[gn] * p.bias_scale;
          }
        }
        if (p.Resr) vr += p.Resr[idx];
        if (HAS_CI && p.Resi) vi += p.Resi[idx];
        if (p.gelu) {
          vr = gelu_f(vr);
          if (HAS_CI) vi = gelu_f(vi);
        }
        if (p.wb32 && p.Cr32) p.Cr32[idx] = vr;
        if (p.wb32 && HAS_CI && p.Ci32) p.Ci32[idx] = vi;
        if (p.Crh) {
          const u16 hh = f2bf(vr);
          p.Crh[idx] = hh;
          if (p.Crl) p.Crl[idx] = f2bf(vr - bf2f(hh));
        }
        if (HAS_CI && p.Cih) {
          const u16 hh = f2bf(vi);
          p.Cih[idx] = hh;
          if (p.Cil) p.Cil[idx] = f2bf(vi - bf2f(hh));
        }
      }
    }
  }
}

// ---------------- pointwise kernels ----------------
struct CvtBatch {
  const float* src[12];
  u16* hi[12];
  u16* lo[12];
  i64 cum[13];
};
__global__ __launch_bounds__(256) void cvt_batch_kernel(CvtBatch b) {
  const i64 k = (i64)blockIdx.x * 1024 + (i64)threadIdx.x * 4;
  int s = 0;
  while (k >= b.cum[s + 1]) ++s;  // all segment sizes are multiples of 1024
  const i64 base = k - b.cum[s];
  float4 v = *(const float4*)(b.src[s] + base);
  u16* hp = b.hi[s];
  u16* lp = b.lo[s];
  ushort4 h, l;
  h.x = f2bf(v.x); l.x = f2bf(v.x - bf2f(h.x));
  h.y = f2bf(v.y); l.y = f2bf(v.y - bf2f(h.y));
  h.z = f2bf(v.z); l.z = f2bf(v.z - bf2f(h.z));
  h.w = f2bf(v.w); l.w = f2bf(v.w - bf2f(h.w));
  *(ushort4*)(hp + base) = h;
  if (lp) *(ushort4*)(lp + base) = l;
}

// standalone convert (used for Hm -> Xh AFTER scores region is dead — liveness invariant!)
__global__ __launch_bounds__(256) void cvt_split_kernel(const float* in, u16* hi, u16* lo,
                                                        i64 n, const float* scale_ptr) {
  const i64 base = (i64)blockIdx.x * 1024 + (i64)threadIdx.x * 4;
  const float s = scale_ptr ? *scale_ptr : 1.0f;
#pragma unroll
  for (int e = 0; e < 4; ++e) {
    const i64 k = base + e;
    if (k < n) {
      const float v = in[k] * s;
      const u16 h = f2bf(v);
      hi[k] = h;
      if (lo) lo[k] = f2bf(v - bf2f(h));
    }
  }
}

// x[b][j][d] fp32 -> xT[b][d][j] bf16 hi/lo  (32x32 LDS tile transpose)
__global__ __launch_bounds__(256) void trans_cvt_kernel(const float* in, u16* outh, u16* outl) {
  __shared__ float t[32][33];
  const int b = blockIdx.z;
  const int j0 = blockIdx.y * 32;
  const int d0 = blockIdx.x * 32;
  const int r = threadIdx.x >> 5, c = threadIdx.x & 31;
  const float* ip = in + (i64)b * 1048576;
#pragma unroll
  for (int it = 0; it < 4; ++it) t[r + it * 8][c] = ip[(i64)(j0 + r + it * 8) * 1024 + d0 + c];
  __syncthreads();
  u16* ohp = outh + (i64)b * 1048576;
  u16* olp = outl + (i64)b * 1048576;
#pragma unroll
  for (int it = 0; it < 4; ++it) {
    const float v = t[c][r + it * 8];
    const i64 o = (i64)(d0 + r + it * 8) * 1024 + j0 + c;
    const u16 h = f2bf(v);
    ohp[o] = h;
    olp[o] = f2bf(v - bf2f(h));
  }
}

__global__ __launch_bounds__(256) void gen_F_kernel(u16* Frh, u16* Frl, u16* Fih, u16* Fil) {
  const int idx = blockIdx.x * 256 + threadIdx.x;
  const int mm = idx >> 10, kk = idx & 1023;
  const int t = (mm * kk) & 1023;
  float sv, cv;
  sincosf((float)t * 6.135923151e-3f, &sv, &cv);  // 2*pi/1024
  const float fr = cv, fi = -sv;
  u16 h = f2bf(fr);
  Frh[idx] = h;
  Frl[idx] = f2bf(fr - bf2f(h));
  h = f2bf(fi);
  Fih[idx] = h;
  Fil[idx] = f2bf(fi - bf2f(h));
}

// U = expm(-iHdt) ~ (I - X^2/2) + i(-X), X=H dt (X^3/6 term ~1e-6 el, dropped)
__global__ __launch_bounds__(256) void assemble_U_kernel(const float* X2m, const float* Hm,
                                                         const float* dtp, u16* Urh, u16* Uih) {
  const int idx = blockIdx.x * 256 + threadIdx.x;
  const int i = idx >> 10, j = idx & 1023;
  const float dt = *dtp;
  const float ur = ((i == j) ? 1.0f : 0.0f) - 0.5f * X2m[idx];
  const float ui = -dt * Hm[idx];
  Urh[idx] = f2bf(ur);
  Uih[idx] = f2bf(ui);
}

// softmax over 1024 fp32, writes bf16 probs in-place at row start (row stride stays 4KB)
__global__ __launch_bounds__(256) void softmax_kernel(float* S) {
  float* row = S + (i64)blockIdx.x * 1024;
  const int t = threadIdx.x;
  float4 v = *(float4*)(row + t * 4);
  float m = fmaxf(fmaxf(v.x, v.y), fmaxf(v.z, v.w));
#pragma unroll
  for (int off = 32; off > 0; off >>= 1) m = fmaxf(m, __shfl_down(m, off));
  __shared__ float red[8];
  const int lane = t & 63, w = t >> 6;
  if (lane == 0) red[w] = m;
  __syncthreads();
  if (t == 0) red[4] = fmaxf(fmaxf(red[0], red[1]), fmaxf(red[2], red[3]));
  __syncthreads();
  m = red[4];
  v.x = expf(v.x - m);
  v.y = expf(v.y - m);
  v.z = expf(v.z - m);
  v.w = expf(v.w - m);
  float s = v.x + v.y + v.z + v.w;
#pragma unroll
  for (int off = 32; off > 0; off >>= 1) s += __shfl_down(s, off);
  if (lane == 0) red[w] = s;
  __syncthreads();
  if (t == 0) red[5] = red[0] + red[1] + red[2] + red[3];
  __syncthreads();
  const float inv = 1.0f / red[5];
  ushort4 o;
  o.x = f2bf(v.x * inv);
  o.y = f2bf(v.y * inv);
  o.z = f2bf(v.z * inv);
  o.w = f2bf(v.w * inv);
  *(ushort4*)((u16*)row + t * 4) = o;
}

// ---------------- host side ----------------
static void run_gemm(hipStream_t s, int cmode, int split, int deep, const GemmP& p, int Z) {
  dim3 g((unsigned)(p.N >> 6), (unsigned)(p.M >> 7), (unsigned)Z);
  dim3 b(256, 1, 1);
  if (split) {
    if (deep) hipLaunchKernelGGL(HIP_KERNEL_NAME(cgemm_kernel<0, 1, 1>), g, b, 0, s, p);
    else hipLaunchKernelGGL(HIP_KERNEL_NAME(cgemm_kernel<1, 1, 0>), g, b, 0, s, p);
  } else {
    if (cmode == 0) hipLaunchKernelGGL(HIP_KERNEL_NAME(cgemm_kernel<0, 0, 1>), g, b, 0, s, p);
    else if (cmode == 1) hipLaunchKernelGGL(HIP_KERNEL_NAME(cgemm_kernel<1, 0, 1>), g, b, 0, s, p);
    else if (cmode == 2) hipLaunchKernelGGL(HIP_KERNEL_NAME(cgemm_kernel<2, 0, 1>), g, b, 0, s, p);
    else hipLaunchKernelGGL(HIP_KERNEL_NAME(cgemm_kernel<3, 0, 1>), g, b, 0, s, p);
  }
}

extern "C" void kernel_launch(void* const* d_in, const int* in_sizes, int n_in, void* d_out,
                              int out_size, void* d_ws, size_t ws_size, hipStream_t stream) {
  (void)in_sizes; (void)n_in; (void)out_size; (void)ws_size;
  const float* x_real = (const float*)d_in[0];
  const float* x_imag = (const float*)d_in[1];
  const float* Wr_q = (const float*)d_in[2];
  const float* Wi_q = (const float*)d_in[3];
  const float* br_q = (const float*)d_in[4];
  const float* bi_q = (const float*)d_in[5];
  const float* Wr_k = (const float*)d_in[6];
  const float* Wi_k = (const float*)d_in[7];
  const float* br_k = (const float*)d_in[8];
  const float* bi_k = (const float*)d_in[9];
  const float* Wr_v = (const float*)d_in[10];
  const float* Wi_v = (const float*)d_in[11];
  const float* br_v = (const float*)d_in[12];
  const float* bi_v = (const float*)d_in[13];
  const float* Wr_o = (const float*)d_in[14];
  const float* Wi_o = (const float*)d_in[15];
  const float* br_o = (const float*)d_in[16];
  const float* bi_o = (const float*)d_in[17];
  const float* Wr_f1 = (const float*)d_in[18];
  const float* Wi_f1 = (const float*)d_in[19];
  const float* br_f1 = (const float*)d_in[20];
  const float* bi_f1 = (const float*)d_in[21];
  const float* Wr_f2 = (const float*)d_in[22];
  const float* Wi_f2 = (const float*)d_in[23];
  const float* br_f2 = (const float*)d_in[24];
  const float* bi_f2 = (const float*)d_in[25];
  const float* Hm = (const float*)d_in[26];
  const float* dtp = (const float*)d_in[27];

  const size_t MBy = 1ull << 20;
  char* W = (char*)d_ws;
  auto U16 = [&](size_t mb) { return (u16*)(W + mb * MBy); };
  auto F32p = [&](size_t mb) { return (float*)(W + mb * MBy); };

  // zone 1 [0,128MB): scores fp32 region, time-shared with transients.
  // LIVENESS INVARIANT: anything here that is READ after the scores GEMM must be
  // WRITTEN after PV (last scores reader). Xh/X2m/U obey this (written post-f2).
  float* scores = F32p(0);
  u16 *xT_rh = U16(0), *xT_ih = U16(4), *xT_rl = U16(8), *xT_il = U16(12);
  u16 *Wq_rh = U16(16), *Wq_ih = U16(18), *Wq_rl = U16(20), *Wq_il = U16(22);
  u16 *Wk_rh = U16(24), *Wk_ih = U16(26), *Wk_rl = U16(28), *Wk_il = U16(30);
  u16 *xf_rh = U16(32), *xf_ih = U16(36), *xf_rl = U16(40), *xf_il = U16(44);
  u16 *h_r = U16(64), *h_i = U16(80);
  u16 *x2_rh = U16(96), *x2_ih = U16(100), *x2_rl = U16(104), *x2_il = U16(108);
  u16* Xh = U16(112);
  float* X2m = F32p(114);
  u16 *Urh = U16(124), *Uih = U16(126);
  // zone 2 [128MB,256MB): persistent
  u16 *Wv_rh = U16(128), *Wv_ih = U16(130);
  u16 *Wo_rh = U16(132), *Wo_ih = U16(134);
  u16 *Wf1_rh = U16(136), *Wf1_ih = U16(144);
  u16 *Wf2_rh = U16(152), *Wf2_ih = U16(160);
  u16 *F_rh = U16(168), *F_ih = U16(170), *F_rl = U16(172), *F_il = U16(174);
  u16 *Qf_rh = U16(176), *Qf_ih = U16(180), *Qf_rl = U16(184), *Qf_il = U16(188);
  u16 *Kf_rh = U16(192), *Kf_ih = U16(196), *Kf_rl = U16(200), *Kf_il = U16(204);
  u16 *VfT_r = U16(208), *VfT_i = U16(212);  // [b][d][seq]
  u16 *ofT_r = U16(216), *ofT_i = U16(220);  // [b][d][seq]
  u16 *ot_r = U16(224), *ot_i = U16(228);    // [b*seq][d]
  float* x1_r = F32p(232);
  float* x1_i = F32p(240);
  u16 *x1h_r = U16(248), *x1h_i = U16(252);

  // ---- batched conversions (weights ONLY — Hm deferred past scores lifetime) ----
  {
    CvtBatch b{};
    const float* srcs[12] = {Wr_q, Wi_q, Wr_k, Wi_k, Wr_v, Wi_v, Wr_o, Wi_o,
                             Wr_f1, Wi_f1, Wr_f2, Wi_f2};
    u16* his[12] = {Wq_rh, Wq_ih, Wk_rh, Wk_ih, Wv_rh, Wv_ih, Wo_rh, Wo_ih,
                    Wf1_rh, Wf1_ih, Wf2_rh, Wf2_ih};
    u16* los[12] = {Wq_rl, Wq_il, Wk_rl, Wk_il, nullptr, nullptr, nullptr, nullptr,
                    nullptr, nullptr, nullptr, nullptr};
    const i64 sizes[12] = {1048576, 1048576, 1048576, 1048576, 1048576, 1048576, 1048576,
                           1048576, 4194304, 4194304, 4194304, 4194304};
    i64 c = 0;
    for (int i = 0; i < 12; ++i) {
      b.src[i] = srcs[i]; b.hi[i] = his[i]; b.lo[i] = los[i];
      b.cum[i] = c; c += sizes[i];
    }
    b.cum[12] = c;
    hipLaunchKernelGGL(cvt_batch_kernel, dim3((unsigned)(c / 1024)), dim3(256), 0, stream, b);
  }
  hipLaunchKernelGGL(trans_cvt_kernel, dim3(32, 32, 2), dim3(256), 0, stream, x_real, xT_rh, xT_rl);
  hipLaunchKernelGGL(trans_cvt_kernel, dim3(32, 32, 2), dim3(256), 0, stream, x_imag, xT_ih, xT_il);
  hipLaunchKernelGGL(gen_F_kernel, dim3(4096), dim3(256), 0, stream, F_rh, F_rl, F_ih, F_il);

  GemmP p;
  auto clearp = [&]() {
    p = GemmP{};
    p.alpha = 1.0f;
    p.ZH = 1;
  };

  // ---- DFT: xf[b] = F @ x[b], fused bf16x2 (A=F h/l, B=xT h/l) ----
  clearp();
  p.M = 1024; p.N = 1024; p.K = 1024; p.lda = 1024; p.ldb = 1024; p.ldc = 1024;
  p.sB1 = 1048576; p.sC1 = 1048576;
  p.Arh = F_rh; p.Aih = F_ih; p.Arl = F_rl; p.Ail = F_il;
  p.Brh = xT_rh; p.Bih = xT_ih; p.Brl = xT_rl; p.Bil = xT_il; p.splitB = 1;
  p.Crh = xf_rh; p.Cih = xf_ih; p.Crl = xf_rl; p.Cil = xf_il;
  run_gemm(stream, 0, 1, 1, p, 2);

  // ---- Q/K projections, fused bf16x2 ----
  auto proj = [&](const u16* Wrh, const u16* Wih, const u16* Wrl, const u16* Wil,
                  const float* br, const float* bi, u16* Orh, u16* Oih, u16* Orl, u16* Oil) {
    clearp();
    p.M = 2048; p.N = 1024; p.K = 1024; p.lda = 1024; p.ldb = 1024; p.ldc = 1024;
    p.Arh = xf_rh; p.Aih = xf_ih; p.Arl = xf_rl; p.Ail = xf_il;
    p.Brh = Wrh; p.Bih = Wih; p.Brl = Wrl; p.Bil = Wil; p.splitB = 1;
    p.bias_mode = 2; p.bias_period = 1024; p.bias_scale = 1024.0f;
    p.biasr = br; p.biasi = bi;
    p.Crh = Orh; p.Cih = Oih; p.Crl = Orl; p.Cil = Oil;
    run_gemm(stream, 0, 1, 1, p, 1);
  };
  proj(Wq_rh, Wq_ih, Wq_rl, Wq_il, br_q, bi_q, Qf_rh, Qf_ih, Qf_rl, Qf_il);
  proj(Wk_rh, Wk_ih, Wk_rl, Wk_il, br_k, bi_k, Kf_rh, Kf_ih, Kf_rl, Kf_il);

  // ---- V projection (plain), TRANSPOSED output VfT[b][d][seq] ----
  clearp();
  p.M = 1024; p.N = 1024; p.K = 1024; p.lda = 1024; p.ldb = 1024; p.ldc = 1024;
  p.sA1 = 1048576; p.sC1 = 1048576;
  p.Arh = xf_rh; p.Aih = xf_ih; p.Brh = Wv_rh; p.Bih = Wv_ih;
  p.bias_mode = 2; p.bias_period = 1024; p.bias_scale = 1024.0f;
  p.biasr = br_v; p.biasi = bi_v;
  p.ctrans = 1;
  p.Crh = VfT_r; p.Cih = VfT_i;
  run_gemm(stream, 0, 0, 1, p, 2);

  // ---- scores = 0.125 * Re(Qf conj(Kf)^T) per head, fused bf16x2 ----
  clearp();
  p.M = 1024; p.N = 1024; p.K = 64; p.lda = 1024; p.ldb = 1024; p.ldc = 1024;
  p.ZH = 16;
  p.sA1 = 1048576; p.sA2 = 64; p.sB1 = 1048576; p.sB2 = 64;
  p.sC1 = 16ll * 1048576; p.sC2 = 1048576;
  p.alpha = 0.125f;
  p.Arh = Qf_rh; p.Aih = Qf_ih; p.Arl = Qf_rl; p.Ail = Qf_il;
  p.Brh = Kf_rh; p.Bih = Kf_ih; p.Brl = Kf_rl; p.Bil = Kf_il; p.splitB = 1;
  p.Cr32 = scores; p.wb32 = 1;
  run_gemm(stream, 1, 1, 0, p, 32);

  hipLaunchKernelGGL(softmax_kernel, dim3(32768), dim3(256), 0, stream, scores);

  // ---- PV: out_f = P @ Vf, P bf16 in-place (lda u16 = 2048), out transposed ofT ----
  clearp();
  p.M = 1024; p.N = 64; p.K = 1024; p.lda = 2048; p.ldb = 1024; p.ldc = 1024;
  p.ZH = 16;
  p.sA1 = 16ll * 2097152; p.sA2 = 2097152;
  p.sB1 = 1048576; p.sB2 = 65536;
  p.sC1 = 1048576; p.sC2 = 65536;
  p.ctrans = 1;
  p.Arh = (const u16*)scores; p.Brh = VfT_r; p.Bih = VfT_i;
  p.Crh = ofT_r; p.Cih = ofT_i;
  run_gemm(stream, 2, 0, 1, p, 32);

  // ---- IDFT: ot[b] = (1/N) conj(F) @ of[b] ----
  clearp();
  p.M = 1024; p.N = 1024; p.K = 1024; p.lda = 1024; p.ldb = 1024; p.ldc = 1024;
  p.sB1 = 1048576; p.sC1 = 1048576;
  p.alpha = 1.0f / 1024.0f;
  p.Arh = F_rh; p.Aih = F_ih; p.Brh = ofT_r; p.Bih = ofT_i;
  p.Crh = ot_r; p.Cih = ot_i;
  run_gemm(stream, 3, 0, 1, p, 2);

  // ---- x1 = x + ot @ Wo^T + b_o ----
  clearp();
  p.M = 2048; p.N = 1024; p.K = 1024; p.lda = 1024; p.ldb = 1024; p.ldc = 1024;
  p.Arh = ot_r; p.Aih = ot_i; p.Brh = Wo_rh; p.Bih = Wo_ih;
  p.bias_mode = 1; p.biasr = br_o; p.biasi = bi_o;
  p.Resr = x_real; p.Resi = x_imag;
  p.Cr32 = x1_r; p.Ci32 = x1_i; p.wb32 = 1; p.Crh = x1h_r; p.Cih = x1h_i;
  run_gemm(stream, 0, 0, 1, p, 1);

  // ---- h = gelu(x1 @ Wf1^T + b_f1) ----
  clearp();
  p.M = 2048; p.N = 4096; p.K = 1024; p.lda = 1024; p.ldb = 1024; p.ldc = 4096;
  p.Arh = x1h_r; p.Aih = x1h_i; p.Brh = Wf1_rh; p.Bih = Wf1_ih;
  p.bias_mode = 1; p.biasr = br_f1; p.biasi = bi_f1;
  p.gelu = 1;
  p.Crh = h_r; p.Cih = h_i;
  run_gemm(stream, 0, 0, 1, p, 1);

  // ---- x2 = x1 + h @ Wf2^T + b_f2 (emit x2 hi/lo) ----
  clearp();
  p.M = 2048; p.N = 1024; p.K = 4096; p.lda = 4096; p.ldb = 4096; p.ldc = 1024;
  p.Arh = h_r; p.Aih = h_i; p.Brh = Wf2_rh; p.Bih = Wf2_ih;
  p.bias_mode = 1; p.biasr = br_f2; p.biasi = bi_f2;
  p.Resr = x1_r; p.Resi = x1_i;
  p.Crh = x2_rh; p.Cih = x2_ih; p.Crl = x2_rl; p.Cil = x2_il;
  run_gemm(stream, 0, 0, 1, p, 1);

  // ---- Xh = bf16(H*dt) — NOW safe: scores region dead (PV was last reader) ----
  hipLaunchKernelGGL(cvt_split_kernel, dim3(1024), dim3(256), 0, stream, Hm, Xh,
                     (u16*)nullptr, (i64)1048576, dtp);

  // ---- X2 = X @ X (X symmetric -> NT) ----
  clearp();
  p.M = 1024; p.N = 1024; p.K = 1024; p.lda = 1024; p.ldb = 1024; p.ldc = 1024;
  p.Arh = Xh; p.Brh = Xh;
  p.Cr32 = X2m; p.wb32 = 1;
  run_gemm(stream, 1, 0, 1, p, 1);
  hipLaunchKernelGGL(assemble_U_kernel, dim3(4096), dim3(256), 0, stream, X2m, Hm, dtp, Urh, Uih);

  // ---- out = x2 @ U (U symmetric -> NT), fused split-A single pass ----
  float* out_r = (float*)d_out;
  float* out_i = out_r + 2097152;
  clearp();
  p.M = 2048; p.N = 1024; p.K = 1024; p.lda = 1024; p.ldb = 1024; p.ldc = 1024;
  p.Arh = x2_rh; p.Aih = x2_ih; p.Arl = x2_rl; p.Ail = x2_il;
  p.Brh = Urh; p.Bih = Uih; p.splitB = 0;
  p.Cr32 = out_r; p.Ci32 = out_i; p.wb32 = 1;
  run_gemm(stream, 0, 1, 1, p, 1);
}

// Round 7
// 909.424 us; speedup vs baseline: 1.6067x; 1.4458x over previous
//
#include <hip/hip_runtime.h>
#include <cstdint>
#include <cstddef>

typedef unsigned int u32;
typedef unsigned short u16;
typedef long long i64;

typedef __attribute__((ext_vector_type(8))) short short8;
typedef __attribute__((ext_vector_type(4))) float f32x4;
typedef __attribute__((ext_vector_type(4))) int i32x4;

// ---------------- device helpers ----------------
__device__ __forceinline__ u16 f2bf(float f) {
  u32 u = __float_as_uint(f);
  u = (u + 0x7FFFu + ((u >> 16) & 1u)) >> 16;  // RNE
  return (u16)u;
}
__device__ __forceinline__ float bf2f(u16 h) { return __uint_as_float(((u32)h) << 16); }

__device__ __forceinline__ short8 neg8(short8 v) {
  i32x4 u = __builtin_bit_cast(i32x4, v);
  u = u ^ (int)0x80008000u;
  return __builtin_bit_cast(short8, u);
}
__device__ __forceinline__ f32x4 mfma16(short8 a, short8 b, f32x4 c) {
  return __builtin_amdgcn_mfma_f32_16x16x32_bf16(a, b, c, 0, 0, 0);
}
__device__ __forceinline__ float gelu_f(float x) {
  return 0.5f * x * (1.0f + erff(x * 0.7071067811865475f));
}
// async global->LDS, 16B/lane; LDS dest = wave-uniform base + lane*16 (LINEAR — m104)
__device__ __forceinline__ void gl16(const u16* g, u16* l) {
  __builtin_amdgcn_global_load_lds((const __attribute__((address_space(1))) void*)g,
                                   (__attribute__((address_space(3))) void*)l, 16, 0, 0);
}
// counted vmcnt wait fused with raw barrier: single opaque asm so no memory op
// (ds_read / global_load_lds) can be scheduled across it (rule #18 class hazard).
template <int N>
__device__ __forceinline__ void wait_barrier() {
  asm volatile("s_waitcnt vmcnt(%0)\n\ts_barrier" ::"i"(N) : "memory");
}

// ---------------- generic complex GEMM ----------------
// C[m,n] = sum_k op(A)[m,k] op(B)[n,k]   (B is [N,K] row-major)
// CMODE 0 CMUL : Cr=ArBr-AiBi, Ci=ArBi+AiBr
// CMODE 1 CONJR: Cr=ArBr+AiBi (split) / ArBr (nonsplit real*real)
// CMODE 2 REALA: Cr=A*Br, Ci=A*Bi (A real bf16)
// CMODE 3 CONJA: Cr=ArBr+AiBi, Ci=ArBi-AiBr
// SPLIT=1 DEEP=1: R4-VERIFIED 128x64-tile depth-3 A+B-in-LDS pipeline.
// SPLIT=0 DEEP=1: 64x64-tile depth-3 A+B-in-LDS pipeline, 2x2 wave layout.
//   R5/R6 post-mortem: direct-global B (JIT or reg-prefetched) is 2x WORSE than
//   B-in-LDS -> reverted. R4 re-analysis: f2 at 2223cyc/K-step with LDS+MFMA only
//   ~600cyc => latency-bound at 1 wave/SIMD (grid 256 = 1 block/CU). f1 (2x FLOPs,
//   4 blocks/CU) is faster than f2 => occupancy is the binding constraint. 64x64
//   tile doubles grid -> 2 blocks/CU -> 2 waves/SIMD fills the stalls.
// SPLIT=1 DEEP=0: verified single-buffered two-barrier loop (scores only).
struct GemmP {
  const u16 *Arh, *Aih, *Arl, *Ail;
  const u16 *Brh, *Bih, *Brl, *Bil;
  const float *biasr, *biasi;
  const float *Resr, *Resi;
  float *Cr32, *Ci32;
  u16 *Crh, *Cih, *Crl, *Cil;
  i64 sA1, sA2, sB1, sB2, sC1, sC2;
  int ZH;
  int M, N, K, lda, ldb, ldc;
  float alpha;
  int beta, wb32, ctrans, bias_mode, bias_period, gelu, splitB;
  float bias_scale;
};

template <int CMODE, int SPLIT, int DEEP>
__global__ __launch_bounds__(256, 2) void cgemm_kernel(GemmP p) {
  constexpr bool HAS_CI = (CMODE == 0 || CMODE == 2 || CMODE == 3);
  constexpr bool AI = (CMODE == 0 || CMODE == 3);
  constexpr bool BIc = (CMODE == 0 || CMODE == 2 || CMODE == 3);
  // split: 48KB buffer (A 4 comps + B up to 4 comps). nonsplit: 16KB (A_r/A_i/B_r/B_i).
  constexpr int BUFU = SPLIT ? 24576 : 8192;
  constexpr int NBUF = DEEP ? 3 : 1;
  __shared__ u16 smem[BUFU * NBUF];
  constexpr int LPS64 = 2 + (AI ? 1 : 0) + (BIc ? 1 : 0);  // gl16/stage/wave nonsplit
  constexpr int NJ = SPLIT ? 4 : 2;  // B-fragment count per wave

  const int tid = threadIdx.x, lane = tid & 63, wave = tid >> 6;
  const int lrow = lane & 15, quad = lane >> 4;
  const int wr = wave >> 1, wc = wave & 1;  // nonsplit 2x2 wave layout
  const int m0 = blockIdx.y * (SPLIT ? 128 : 64);
  const int n0 = blockIdx.x * 64;
  const int z1 = blockIdx.z / p.ZH, z2 = blockIdx.z % p.ZH;
  const i64 zA = (i64)z1 * p.sA1 + (i64)z2 * p.sA2;
  const i64 zB = (i64)z1 * p.sB1 + (i64)z2 * p.sB2;
  const i64 zC = (i64)z1 * p.sC1 + (i64)z2 * p.sC2;
  const int l4 = lane >> 2;
  // DEEP: pre-swizzled global source chunk (both-sides-or-neither, m104/m231):
  // LDS slot (row r, chunk c) holds logical chunk c ^ ((r>>1)&3); reads XOR same term.
  const int lc = DEEP ? ((((lane & 3) ^ ((lane >> 3) & 3))) << 3) : ((lane & 3) << 3);
  // split: each wave stages 32 A-rows (two 16-row groups); nonsplit: 16 A-rows.
  const i64 aoff0 = zA + (i64)(m0 + (SPLIT ? 32 : 16) * wave + l4) * p.lda + lc;
  const i64 aoff1 = aoff0 + (i64)16 * p.lda;  // split only
  const i64 boff = zB + (i64)(n0 + 16 * wave + l4) * p.ldb + lc;
  const int lA0 = (SPLIT ? 1024 : 512) * wave, lA1 = lA0 + 512;
  const int lB0 = 512 * wave;
  const int cxw = ((lrow >> 1) & 3) << 3;  // read-side swizzle XOR (u16 units)

  f32x4 accR[2][NJ], accI[2][NJ];
  const f32x4 z4 = {0.f, 0.f, 0.f, 0.f};
#pragma unroll
  for (int i = 0; i < 2; ++i)
#pragma unroll
    for (int j = 0; j < NJ; ++j) { accR[i][j] = z4; accI[i][j] = z4; }

  const int ktn = p.K >> 5;

  if constexpr (SPLIT && !DEEP) {
    // ---- verified single-buffered two-barrier loop (scores path) ----
    for (int kt = 0; kt < ktn; ++kt) {
      const i64 kc = (i64)(kt << 5);
      __syncthreads();  // all waves done reading previous tile
      gl16(p.Arh + aoff0 + kc, smem + lA0);
      gl16(p.Arh + aoff1 + kc, smem + lA1);
      gl16(p.Aih + aoff0 + kc, smem + 4096 + lA0);
      gl16(p.Aih + aoff1 + kc, smem + 4096 + lA1);
      gl16(p.Arl + aoff0 + kc, smem + 8192 + lA0);
      gl16(p.Arl + aoff1 + kc, smem + 8192 + lA1);
      gl16(p.Ail + aoff0 + kc, smem + 12288 + lA0);
      gl16(p.Ail + aoff1 + kc, smem + 12288 + lA1);
      gl16(p.Brh + boff + kc, smem + 16384 + lB0);
      gl16(p.Bih + boff + kc, smem + 18432 + lB0);
      if (p.splitB) {
        gl16(p.Brl + boff + kc, smem + 20480 + lB0);
        gl16(p.Bil + boff + kc, smem + 22528 + lB0);
      }
      __syncthreads();  // drains vmcnt -> DMA landed

      short8 bRh[4], bIh[4], bRl[4], bIl[4];
#pragma unroll
      for (int j = 0; j < 4; ++j) {
        const int off = (j * 16 + lrow) * 32 + quad * 8;
        bRh[j] = *(const short8*)&smem[16384 + off];
        bIh[j] = *(const short8*)&smem[18432 + off];
        if (p.splitB) {
          bRl[j] = *(const short8*)&smem[20480 + off];
          bIl[j] = *(const short8*)&smem[22528 + off];
        }
      }
#pragma unroll
      for (int i = 0; i < 2; ++i) {
        const int off = (wave * 32 + i * 16 + lrow) * 32 + quad * 8;
        short8 aRh = *(const short8*)&smem[off];
        short8 aIh = *(const short8*)&smem[4096 + off];
        short8 aRl = *(const short8*)&smem[8192 + off];
        short8 aIl = *(const short8*)&smem[12288 + off];
        if constexpr (CMODE == 0) {
          short8 nIh = neg8(aIh), nIl = neg8(aIl);
#pragma unroll
          for (int j = 0; j < 4; ++j) {
            accR[i][j] = mfma16(aRh, bRh[j], accR[i][j]);
            accR[i][j] = mfma16(nIh, bIh[j], accR[i][j]);
            accI[i][j] = mfma16(aRh, bIh[j], accI[i][j]);
            accI[i][j] = mfma16(aIh, bRh[j], accI[i][j]);
            accR[i][j] = mfma16(aRl, bRh[j], accR[i][j]);
            accR[i][j] = mfma16(nIl, bIh[j], accR[i][j]);
            accI[i][j] = mfma16(aRl, bIh[j], accI[i][j]);
            accI[i][j] = mfma16(aIl, bRh[j], accI[i][j]);
            if (p.splitB) {
              accR[i][j] = mfma16(aRh, bRl[j], accR[i][j]);
              accR[i][j] = mfma16(nIh, bIl[j], accR[i][j]);
              accI[i][j] = mfma16(aRh, bIl[j], accI[i][j]);
              accI[i][j] = mfma16(aIh, bRl[j], accI[i][j]);
            }
          }
        } else {  // CONJR split: Re(Q conj(K)) 3-combo
#pragma unroll
          for (int j = 0; j < 4; ++j) {
            accR[i][j] = mfma16(aRh, bRh[j], accR[i][j]);
            accR[i][j] = mfma16(aIh, bIh[j], accR[i][j]);
            accR[i][j] = mfma16(aRl, bRh[j], accR[i][j]);
            accR[i][j] = mfma16(aIl, bIh[j], accR[i][j]);
            accR[i][j] = mfma16(aRh, bRl[j], accR[i][j]);
            accR[i][j] = mfma16(aIh, bIl[j], accR[i][j]);
          }
        }
      }
    }
  } else if constexpr (SPLIT && DEEP) {
    // ---- R4-VERIFIED depth-3 split pipeline: A+B in LDS, buffers at buf*24576 ----
    auto stageS = [&](int buf, i64 kc) {
      u16* s = smem + buf * 24576;
      gl16(p.Arh + aoff0 + kc, s + lA0);
      gl16(p.Arh + aoff1 + kc, s + lA1);
      gl16(p.Aih + aoff0 + kc, s + 4096 + lA0);
      gl16(p.Aih + aoff1 + kc, s + 4096 + lA1);
      gl16(p.Arl + aoff0 + kc, s + 8192 + lA0);
      gl16(p.Arl + aoff1 + kc, s + 8192 + lA1);
      gl16(p.Ail + aoff0 + kc, s + 12288 + lA0);
      gl16(p.Ail + aoff1 + kc, s + 12288 + lA1);
      gl16(p.Brh + boff + kc, s + 16384 + lB0);
      gl16(p.Bih + boff + kc, s + 18432 + lB0);
      if (p.splitB) {
        gl16(p.Brl + boff + kc, s + 20480 + lB0);
        gl16(p.Bil + boff + kc, s + 22528 + lB0);
      }
    };
    if (ktn > 0) stageS(0, 0);
    if (ktn > 1) stageS(1, 32);
    for (int kt = 0; kt < ktn; ++kt) {
      // leave tile kt+1's stage in flight; guarantee tile kt landed + compute(kt-1) done
      if (kt + 1 < ktn) {
        if (p.splitB) wait_barrier<12>(); else wait_barrier<10>();
      } else {
        wait_barrier<0>();
      }
      if (kt + 2 < ktn) stageS((kt + 2) % 3, (i64)((kt + 2) << 5));  // overwrites buf[(kt-1)%3]
      const u16* sb = smem + (kt % 3) * 24576;

      short8 bRh[4], bIh[4], bRl[4], bIl[4];
#pragma unroll
      for (int j = 0; j < 4; ++j) {
        const int off = (j * 16 + lrow) * 32 + (quad * 8 ^ cxw);
        bRh[j] = *(const short8*)&sb[16384 + off];
        bIh[j] = *(const short8*)&sb[18432 + off];
        if (p.splitB) {
          bRl[j] = *(const short8*)&sb[20480 + off];
          bIl[j] = *(const short8*)&sb[22528 + off];
        }
      }
#pragma unroll
      for (int i = 0; i < 2; ++i) {
        const int off = (wave * 32 + i * 16 + lrow) * 32 + (quad * 8 ^ cxw);
        short8 aRh = *(const short8*)&sb[off];
        short8 aIh = *(const short8*)&sb[4096 + off];
        short8 aRl = *(const short8*)&sb[8192 + off];
        short8 aIl = *(const short8*)&sb[12288 + off];
        if constexpr (CMODE == 0) {
          short8 nIh = neg8(aIh), nIl = neg8(aIl);
#pragma unroll
          for (int j = 0; j < 4; ++j) {
            accR[i][j] = mfma16(aRh, bRh[j], accR[i][j]);
            accR[i][j] = mfma16(nIh, bIh[j], accR[i][j]);
            accI[i][j] = mfma16(aRh, bIh[j], accI[i][j]);
            accI[i][j] = mfma16(aIh, bRh[j], accI[i][j]);
            accR[i][j] = mfma16(aRl, bRh[j], accR[i][j]);
            accR[i][j] = mfma16(nIl, bIh[j], accR[i][j]);
            accI[i][j] = mfma16(aRl, bIh[j], accI[i][j]);
            accI[i][j] = mfma16(aIl, bRh[j], accI[i][j]);
            if (p.splitB) {
              accR[i][j] = mfma16(aRh, bRl[j], accR[i][j]);
              accR[i][j] = mfma16(nIh, bIl[j], accR[i][j]);
              accI[i][j] = mfma16(aRh, bIl[j], accI[i][j]);
              accI[i][j] = mfma16(aIh, bRl[j], accI[i][j]);
            }
          }
        } else {  // CONJR split
#pragma unroll
          for (int j = 0; j < 4; ++j) {
            accR[i][j] = mfma16(aRh, bRh[j], accR[i][j]);
            accR[i][j] = mfma16(aIh, bIh[j], accR[i][j]);
            accR[i][j] = mfma16(aRl, bRh[j], accR[i][j]);
            accR[i][j] = mfma16(aIl, bIh[j], accR[i][j]);
            accR[i][j] = mfma16(aRh, bRl[j], accR[i][j]);
            accR[i][j] = mfma16(aIh, bIl[j], accR[i][j]);
          }
        }
      }
    }
  } else {
    // ---- 64x64-tile depth-3 pipeline (2 blocks/CU), A+B in LDS ----
    // buffer (u16): A_r +0, A_i +2048, B_r +4096, B_i +6144. Each wave stages
    // 16 A-rows and 16 B-rows (1 gl16 per component).
    auto stage = [&](int buf, i64 kc) {
      u16* s = smem + buf * 8192;
      gl16(p.Arh + aoff0 + kc, s + lA0);
      if constexpr (AI) gl16(p.Aih + aoff0 + kc, s + 2048 + lA0);
      gl16(p.Brh + boff + kc, s + 4096 + lB0);
      if constexpr (BIc) gl16(p.Bih + boff + kc, s + 6144 + lB0);
    };
    if (ktn > 0) stage(0, 0);
    if (ktn > 1) stage(1, 32);
    for (int kt = 0; kt < ktn; ++kt) {
      if (kt + 1 < ktn) wait_barrier<LPS64>(); else wait_barrier<0>();
      if (kt + 2 < ktn) stage((kt + 2) % 3, (i64)((kt + 2) << 5));
      const u16* sb = smem + (kt % 3) * 8192;

      short8 bR[2], bI[2];
#pragma unroll
      for (int j = 0; j < 2; ++j) {
        const int off = 4096 + (wc * 32 + j * 16 + lrow) * 32 + (quad * 8 ^ cxw);
        bR[j] = *(const short8*)&sb[off];
        if constexpr (BIc) bI[j] = *(const short8*)&sb[off + 2048];
      }
#pragma unroll
      for (int i = 0; i < 2; ++i) {
        const int off = (wr * 32 + i * 16 + lrow) * 32 + (quad * 8 ^ cxw);
        short8 aR = *(const short8*)&sb[off];
        if constexpr (CMODE == 0) {
          short8 aI = *(const short8*)&sb[off + 2048];
          short8 nI = neg8(aI);
#pragma unroll
          for (int j = 0; j < 2; ++j) {
            accR[i][j] = mfma16(aR, bR[j], accR[i][j]);
            accR[i][j] = mfma16(nI, bI[j], accR[i][j]);
            accI[i][j] = mfma16(aR, bI[j], accI[i][j]);
            accI[i][j] = mfma16(aI, bR[j], accI[i][j]);
          }
        } else if constexpr (CMODE == 1) {  // real*real
#pragma unroll
          for (int j = 0; j < 2; ++j) accR[i][j] = mfma16(aR, bR[j], accR[i][j]);
        } else if constexpr (CMODE == 2) {  // A real, B complex
#pragma unroll
          for (int j = 0; j < 2; ++j) {
            accR[i][j] = mfma16(aR, bR[j], accR[i][j]);
            accI[i][j] = mfma16(aR, bI[j], accI[i][j]);
          }
        } else {  // CONJA
          short8 aI = *(const short8*)&sb[off + 2048];
          short8 nI = neg8(aI);
#pragma unroll
          for (int j = 0; j < 2; ++j) {
            accR[i][j] = mfma16(aR, bR[j], accR[i][j]);
            accR[i][j] = mfma16(aI, bI[j], accR[i][j]);
            accI[i][j] = mfma16(aR, bI[j], accI[i][j]);
            accI[i][j] = mfma16(nI, bR[j], accI[i][j]);
          }
        }
      }
    }
  }

  // ---- epilogue ----
#pragma unroll
  for (int i = 0; i < 2; ++i) {
#pragma unroll
    for (int j = 0; j < NJ; ++j) {
      const int gn = SPLIT ? (n0 + j * 16 + lrow) : (n0 + wc * 32 + j * 16 + lrow);
#pragma unroll
      for (int r = 0; r < 4; ++r) {
        const int gm = SPLIT ? (m0 + wave * 32 + i * 16 + quad * 4 + r)
                             : (m0 + wr * 32 + i * 16 + quad * 4 + r);
        const i64 idx = p.ctrans ? (zC + (i64)gn * p.ldc + gm) : (zC + (i64)gm * p.ldc + gn);
        float vr = accR[i][j][r] * p.alpha;
        float vi = 0.f;
        if (HAS_CI) vi = accI[i][j][r] * p.alpha;
        if (p.beta) {
          vr += p.Cr32[idx];
          if (HAS_CI && p.Ci32) vi += p.Ci32[idx];
        }
        if (p.bias_mode == 1) {
          vr += p.biasr[gn];
          if (HAS_CI) vi += p.biasi[gn];
        } else if (p.bias_mode == 2) {
          if ((gm % p.bias_period) == 0) {
            vr += p.biasr[gn] * p.bias_scale;
            if (HAS_CI) vi += p.biasi[gn] * p.bias_scale;
          }
        }
        if (p.Resr) vr += p.Resr[idx];
        if (HAS_CI && p.Resi) vi += p.Resi[idx];
        if (p.gelu) {
          vr = gelu_f(vr);
          if (HAS_CI) vi = gelu_f(vi);
        }
        if (p.wb32 && p.Cr32) p.Cr32[idx] = vr;
        if (p.wb32 && HAS_CI && p.Ci32) p.Ci32[idx] = vi;
        if (p.Crh) {
          const u16 hh = f2bf(vr);
          p.Crh[idx] = hh;
          if (p.Crl) p.Crl[idx] = f2bf(vr - bf2f(hh));
        }
        if (HAS_CI && p.Cih) {
          const u16 hh = f2bf(vi);
          p.Cih[idx] = hh;
          if (p.Cil) p.Cil[idx] = f2bf(vi - bf2f(hh));
        }
      }
    }
  }
}

// ---------------- pointwise kernels ----------------
struct CvtBatch {
  const float* src[12];
  u16* hi[12];
  u16* lo[12];
  i64 cum[13];
};
__global__ __launch_bounds__(256) void cvt_batch_kernel(CvtBatch b) {
  const i64 k = (i64)blockIdx.x * 1024 + (i64)threadIdx.x * 4;
  int s = 0;
  while (k >= b.cum[s + 1]) ++s;  // all segment sizes are multiples of 1024
  const i64 base = k - b.cum[s];
  float4 v = *(const float4*)(b.src[s] + base);
  u16* hp = b.hi[s];
  u16* lp = b.lo[s];
  ushort4 h, l;
  h.x = f2bf(v.x); l.x = f2bf(v.x - bf2f(h.x));
  h.y = f2bf(v.y); l.y = f2bf(v.y - bf2f(h.y));
  h.z = f2bf(v.z); l.z = f2bf(v.z - bf2f(h.z));
  h.w = f2bf(v.w); l.w = f2bf(v.w - bf2f(h.w));
  *(ushort4*)(hp + base) = h;
  if (lp) *(ushort4*)(lp + base) = l;
}

// standalone convert (used for Hm -> Xh AFTER scores region is dead — liveness invariant!)
__global__ __launch_bounds__(256) void cvt_split_kernel(const float* in, u16* hi, u16* lo,
                                                        i64 n, const float* scale_ptr) {
  const i64 base = (i64)blockIdx.x * 1024 + (i64)threadIdx.x * 4;
  const float s = scale_ptr ? *scale_ptr : 1.0f;
#pragma unroll
  for (int e = 0; e < 4; ++e) {
    const i64 k = base + e;
    if (k < n) {
      const float v = in[k] * s;
      const u16 h = f2bf(v);
      hi[k] = h;
      if (lo) lo[k] = f2bf(v - bf2f(h));
    }
  }
}

// x[b][j][d] fp32 -> xT[b][d][j] bf16 hi/lo  (32x32 LDS tile transpose)
__global__ __launch_bounds__(256) void trans_cvt_kernel(const float* in, u16* outh, u16* outl) {
  __shared__ float t[32][33];
  const int b = blockIdx.z;
  const int j0 = blockIdx.y * 32;
  const int d0 = blockIdx.x * 32;
  const int r = threadIdx.x >> 5, c = threadIdx.x & 31;
  const float* ip = in + (i64)b * 1048576;
#pragma unroll
  for (int it = 0; it < 4; ++it) t[r + it * 8][c] = ip[(i64)(j0 + r + it * 8) * 1024 + d0 + c];
  __syncthreads();
  u16* ohp = outh + (i64)b * 1048576;
  u16* olp = outl + (i64)b * 1048576;
#pragma unroll
  for (int it = 0; it < 4; ++it) {
    const float v = t[c][r + it * 8];
    const i64 o = (i64)(d0 + r + it * 8) * 1024 + j0 + c;
    const u16 h = f2bf(v);
    ohp[o] = h;
    olp[o] = f2bf(v - bf2f(h));
  }
}

__global__ __launch_bounds__(256) void gen_F_kernel(u16* Frh, u16* Frl, u16* Fih, u16* Fil) {
  const int idx = blockIdx.x * 256 + threadIdx.x;
  const int mm = idx >> 10, kk = idx & 1023;
  const int t = (mm * kk) & 1023;
  float sv, cv;
  sincosf((float)t * 6.135923151e-3f, &sv, &cv);  // 2*pi/1024
  const float fr = cv, fi = -sv;
  u16 h = f2bf(fr);
  Frh[idx] = h;
  Frl[idx] = f2bf(fr - bf2f(h));
  h = f2bf(fi);
  Fih[idx] = h;
  Fil[idx] = f2bf(fi - bf2f(h));
}

// U = expm(-iHdt) ~ (I - X^2/2) + i(-X), X=H dt (X^3/6 term ~1e-6 el, dropped)
__global__ __launch_bounds__(256) void assemble_U_kernel(const float* X2m, const float* Hm,
                                                         const float* dtp, u16* Urh, u16* Uih) {
  const int idx = blockIdx.x * 256 + threadIdx.x;
  const int i = idx >> 10, j = idx & 1023;
  const float dt = *dtp;
  const float ur = ((i == j) ? 1.0f : 0.0f) - 0.5f * X2m[idx];
  const float ui = -dt * Hm[idx];
  Urh[idx] = f2bf(ur);
  Uih[idx] = f2bf(ui);
}

// softmax over 1024 fp32, writes bf16 probs in-place at row start (row stride stays 4KB)
__global__ __launch_bounds__(256) void softmax_kernel(float* S) {
  float* row = S + (i64)blockIdx.x * 1024;
  const int t = threadIdx.x;
  float4 v = *(float4*)(row + t * 4);
  float m = fmaxf(fmaxf(v.x, v.y), fmaxf(v.z, v.w));
#pragma unroll
  for (int off = 32; off > 0; off >>= 1) m = fmaxf(m, __shfl_down(m, off));
  __shared__ float red[8];
  const int lane = t & 63, w = t >> 6;
  if (lane == 0) red[w] = m;
  __syncthreads();
  if (t == 0) red[4] = fmaxf(fmaxf(red[0], red[1]), fmaxf(red[2], red[3]));
  __syncthreads();
  m = red[4];
  v.x = expf(v.x - m);
  v.y = expf(v.y - m);
  v.z = expf(v.z - m);
  v.w = expf(v.w - m);
  float s = v.x + v.y + v.z + v.w;
#pragma unroll
  for (int off = 32; off > 0; off >>= 1) s += __shfl_down(s, off);
  if (lane == 0) red[w] = s;
  __syncthreads();
  if (t == 0) red[5] = red[0] + red[1] + red[2] + red[3];
  __syncthreads();
  const float inv = 1.0f / red[5];
  ushort4 o;
  o.x = f2bf(v.x * inv);
  o.y = f2bf(v.y * inv);
  o.z = f2bf(v.z * inv);
  o.w = f2bf(v.w * inv);
  *(ushort4*)((u16*)row + t * 4) = o;
}

// ---------------- host side ----------------
static void run_gemm(hipStream_t s, int cmode, int split, int deep, const GemmP& p, int Z) {
  // split: 128-row tiles; nonsplit: 64-row tiles (2 blocks/CU occupancy)
  dim3 g((unsigned)(p.N >> 6), (unsigned)(p.M >> (split ? 7 : 6)), (unsigned)Z);
  dim3 b(256, 1, 1);
  if (split) {
    if (deep) hipLaunchKernelGGL(HIP_KERNEL_NAME(cgemm_kernel<0, 1, 1>), g, b, 0, s, p);
    else hipLaunchKernelGGL(HIP_KERNEL_NAME(cgemm_kernel<1, 1, 0>), g, b, 0, s, p);
  } else {
    if (cmode == 0) hipLaunchKernelGGL(HIP_KERNEL_NAME(cgemm_kernel<0, 0, 1>), g, b, 0, s, p);
    else if (cmode == 1) hipLaunchKernelGGL(HIP_KERNEL_NAME(cgemm_kernel<1, 0, 1>), g, b, 0, s, p);
    else if (cmode == 2) hipLaunchKernelGGL(HIP_KERNEL_NAME(cgemm_kernel<2, 0, 1>), g, b, 0, s, p);
    else hipLaunchKernelGGL(HIP_KERNEL_NAME(cgemm_kernel<3, 0, 1>), g, b, 0, s, p);
  }
}

extern "C" void kernel_launch(void* const* d_in, const int* in_sizes, int n_in, void* d_out,
                              int out_size, void* d_ws, size_t ws_size, hipStream_t stream) {
  (void)in_sizes; (void)n_in; (void)out_size; (void)ws_size;
  const float* x_real = (const float*)d_in[0];
  const float* x_imag = (const float*)d_in[1];
  const float* Wr_q = (const float*)d_in[2];
  const float* Wi_q = (const float*)d_in[3];
  const float* br_q = (const float*)d_in[4];
  const float* bi_q = (const float*)d_in[5];
  const float* Wr_k = (const float*)d_in[6];
  const float* Wi_k = (const float*)d_in[7];
  const float* br_k = (const float*)d_in[8];
  const float* bi_k = (const float*)d_in[9];
  const float* Wr_v = (const float*)d_in[10];
  const float* Wi_v = (const float*)d_in[11];
  const float* br_v = (const float*)d_in[12];
  const float* bi_v = (const float*)d_in[13];
  const float* Wr_o = (const float*)d_in[14];
  const float* Wi_o = (const float*)d_in[15];
  const float* br_o = (const float*)d_in[16];
  const float* bi_o = (const float*)d_in[17];
  const float* Wr_f1 = (const float*)d_in[18];
  const float* Wi_f1 = (const float*)d_in[19];
  const float* br_f1 = (const float*)d_in[20];
  const float* bi_f1 = (const float*)d_in[21];
  const float* Wr_f2 = (const float*)d_in[22];
  const float* Wi_f2 = (const float*)d_in[23];
  const float* br_f2 = (const float*)d_in[24];
  const float* bi_f2 = (const float*)d_in[25];
  const float* Hm = (const float*)d_in[26];
  const float* dtp = (const float*)d_in[27];

  const size_t MBy = 1ull << 20;
  char* W = (char*)d_ws;
  auto U16 = [&](size_t mb) { return (u16*)(W + mb * MBy); };
  auto F32p = [&](size_t mb) { return (float*)(W + mb * MBy); };

  // zone 1 [0,128MB): scores fp32 region, time-shared with transients.
  // LIVENESS INVARIANT: anything here that is READ after the scores GEMM must be
  // WRITTEN after PV (last scores reader). Xh/X2m/U obey this (written post-f2).
  float* scores = F32p(0);
  u16 *xT_rh = U16(0), *xT_ih = U16(4), *xT_rl = U16(8), *xT_il = U16(12);
  u16 *Wq_rh = U16(16), *Wq_ih = U16(18), *Wq_rl = U16(20), *Wq_il = U16(22);
  u16 *Wk_rh = U16(24), *Wk_ih = U16(26), *Wk_rl = U16(28), *Wk_il = U16(30);
  u16 *xf_rh = U16(32), *xf_ih = U16(36), *xf_rl = U16(40), *xf_il = U16(44);
  u16 *h_r = U16(64), *h_i = U16(80);
  u16 *x2_rh = U16(96), *x2_ih = U16(100), *x2_rl = U16(104), *x2_il = U16(108);
  u16* Xh = U16(112);
  float* X2m = F32p(114);
  u16 *Urh = U16(124), *Uih = U16(126);
  // zone 2 [128MB,256MB): persistent
  u16 *Wv_rh = U16(128), *Wv_ih = U16(130);
  u16 *Wo_rh = U16(132), *Wo_ih = U16(134);
  u16 *Wf1_rh = U16(136), *Wf1_ih = U16(144);
  u16 *Wf2_rh = U16(152), *Wf2_ih = U16(160);
  u16 *F_rh = U16(168), *F_ih = U16(170), *F_rl = U16(172), *F_il = U16(174);
  u16 *Qf_rh = U16(176), *Qf_ih = U16(180), *Qf_rl = U16(184), *Qf_il = U16(188);
  u16 *Kf_rh = U16(192), *Kf_ih = U16(196), *Kf_rl = U16(200), *Kf_il = U16(204);
  u16 *VfT_r = U16(208), *VfT_i = U16(212);  // [b][d][seq]
  u16 *ofT_r = U16(216), *ofT_i = U16(220);  // [b][d][seq]
  u16 *ot_r = U16(224), *ot_i = U16(228);    // [b*seq][d]
  float* x1_r = F32p(232);
  float* x1_i = F32p(240);
  u16 *x1h_r = U16(248), *x1h_i = U16(252);

  // ---- batched conversions (weights ONLY — Hm deferred past scores lifetime) ----
  {
    CvtBatch b{};
    const float* srcs[12] = {Wr_q, Wi_q, Wr_k, Wi_k, Wr_v, Wi_v, Wr_o, Wi_o,
                             Wr_f1, Wi_f1, Wr_f2, Wi_f2};
    u16* his[12] = {Wq_rh, Wq_ih, Wk_rh, Wk_ih, Wv_rh, Wv_ih, Wo_rh, Wo_ih,
                    Wf1_rh, Wf1_ih, Wf2_rh, Wf2_ih};
    u16* los[12] = {Wq_rl, Wq_il, Wk_rl, Wk_il, nullptr, nullptr, nullptr, nullptr,
                    nullptr, nullptr, nullptr, nullptr};
    const i64 sizes[12] = {1048576, 1048576, 1048576, 1048576, 1048576, 1048576, 1048576,
                           1048576, 4194304, 4194304, 4194304, 4194304};
    i64 c = 0;
    for (int i = 0; i < 12; ++i) {
      b.src[i] = srcs[i]; b.hi[i] = his[i]; b.lo[i] = los[i];
      b.cum[i] = c; c += sizes[i];
    }
    b.cum[12] = c;
    hipLaunchKernelGGL(cvt_batch_kernel, dim3((unsigned)(c / 1024)), dim3(256), 0, stream, b);
  }
  hipLaunchKernelGGL(trans_cvt_kernel, dim3(32, 32, 2), dim3(256), 0, stream, x_real, xT_rh, xT_rl);
  hipLaunchKernelGGL(trans_cvt_kernel, dim3(32, 32, 2), dim3(256), 0, stream, x_imag, xT_ih, xT_il);
  hipLaunchKernelGGL(gen_F_kernel, dim3(4096), dim3(256), 0, stream, F_rh, F_rl, F_ih, F_il);

  GemmP p;
  auto clearp = [&]() {
    p = GemmP{};
    p.alpha = 1.0f;
    p.ZH = 1;
  };

  // ---- DFT: xf[b] = F @ x[b], fused bf16x2 (A=F h/l, B=xT h/l) ----
  clearp();
  p.M = 1024; p.N = 1024; p.K = 1024; p.lda = 1024; p.ldb = 1024; p.ldc = 1024;
  p.sB1 = 1048576; p.sC1 = 1048576;
  p.Arh = F_rh; p.Aih = F_ih; p.Arl = F_rl; p.Ail = F_il;
  p.Brh = xT_rh; p.Bih = xT_ih; p.Brl = xT_rl; p.Bil = xT_il; p.splitB = 1;
  p.Crh = xf_rh; p.Cih = xf_ih; p.Crl = xf_rl; p.Cil = xf_il;
  run_gemm(stream, 0, 1, 1, p, 2);

  // ---- Q/K projections, fused bf16x2 ----
  auto proj = [&](const u16* Wrh, const u16* Wih, const u16* Wrl, const u16* Wil,
                  const float* br, const float* bi, u16* Orh, u16* Oih, u16* Orl, u16* Oil) {
    clearp();
    p.M = 2048; p.N = 1024; p.K = 1024; p.lda = 1024; p.ldb = 1024; p.ldc = 1024;
    p.Arh = xf_rh; p.Aih = xf_ih; p.Arl = xf_rl; p.Ail = xf_il;
    p.Brh = Wrh; p.Bih = Wih; p.Brl = Wrl; p.Bil = Wil; p.splitB = 1;
    p.bias_mode = 2; p.bias_period = 1024; p.bias_scale = 1024.0f;
    p.biasr = br; p.biasi = bi;
    p.Crh = Orh; p.Cih = Oih; p.Crl = Orl; p.Cil = Oil;
    run_gemm(stream, 0, 1, 1, p, 1);
  };
  proj(Wq_rh, Wq_ih, Wq_rl, Wq_il, br_q, bi_q, Qf_rh, Qf_ih, Qf_rl, Qf_il);
  proj(Wk_rh, Wk_ih, Wk_rl, Wk_il, br_k, bi_k, Kf_rh, Kf_ih, Kf_rl, Kf_il);

  // ---- V projection (plain), TRANSPOSED output VfT[b][d][seq] ----
  clearp();
  p.M = 1024; p.N = 1024; p.K = 1024; p.lda = 1024; p.ldb = 1024; p.ldc = 1024;
  p.sA1 = 1048576; p.sC1 = 1048576;
  p.Arh = xf_rh; p.Aih = xf_ih; p.Brh = Wv_rh; p.Bih = Wv_ih;
  p.bias_mode = 2; p.bias_period = 1024; p.bias_scale = 1024.0f;
  p.biasr = br_v; p.biasi = bi_v;
  p.ctrans = 1;
  p.Crh = VfT_r; p.Cih = VfT_i;
  run_gemm(stream, 0, 0, 1, p, 2);

  // ---- scores = 0.125 * Re(Qf conj(Kf)^T) per head, fused bf16x2 ----
  clearp();
  p.M = 1024; p.N = 1024; p.K = 64; p.lda = 1024; p.ldb = 1024; p.ldc = 1024;
  p.ZH = 16;
  p.sA1 = 1048576; p.sA2 = 64; p.sB1 = 1048576; p.sB2 = 64;
  p.sC1 = 16ll * 1048576; p.sC2 = 1048576;
  p.alpha = 0.125f;
  p.Arh = Qf_rh; p.Aih = Qf_ih; p.Arl = Qf_rl; p.Ail = Qf_il;
  p.Brh = Kf_rh; p.Bih = Kf_ih; p.Brl = Kf_rl; p.Bil = Kf_il; p.splitB = 1;
  p.Cr32 = scores; p.wb32 = 1;
  run_gemm(stream, 1, 1, 0, p, 32);

  hipLaunchKernelGGL(softmax_kernel, dim3(32768), dim3(256), 0, stream, scores);

  // ---- PV: out_f = P @ Vf, P bf16 in-place (lda u16 = 2048), out transposed ofT ----
  clearp();
  p.M = 1024; p.N = 64; p.K = 1024; p.lda = 2048; p.ldb = 1024; p.ldc = 1024;
  p.ZH = 16;
  p.sA1 = 16ll * 2097152; p.sA2 = 2097152;
  p.sB1 = 1048576; p.sB2 = 65536;
  p.sC1 = 1048576; p.sC2 = 65536;
  p.ctrans = 1;
  p.Arh = (const u16*)scores; p.Brh = VfT_r; p.Bih = VfT_i;
  p.Crh = ofT_r; p.Cih = ofT_i;
  run_gemm(stream, 2, 0, 1, p, 32);

  // ---- IDFT: ot[b] = (1/N) conj(F) @ of[b] ----
  clearp();
  p.M = 1024; p.N = 1024; p.K = 1024; p.lda = 1024; p.ldb = 1024; p.ldc = 1024;
  p.sB1 = 1048576; p.sC1 = 1048576;
  p.alpha = 1.0f / 1024.0f;
  p.Arh = F_rh; p.Aih = F_ih; p.Brh = ofT_r; p.Bih = ofT_i;
  p.Crh = ot_r; p.Cih = ot_i;
  run_gemm(stream, 3, 0, 1, p, 2);

  // ---- x1 = x + ot @ Wo^T + b_o ----
  clearp();
  p.M = 2048; p.N = 1024; p.K = 1024; p.lda = 1024; p.ldb = 1024; p.ldc = 1024;
  p.Arh = ot_r; p.Aih = ot_i; p.Brh = Wo_rh; p.Bih = Wo_ih;
  p.bias_mode = 1; p.biasr = br_o; p.biasi = bi_o;
  p.Resr = x_real; p.Resi = x_imag;
  p.Cr32 = x1_r; p.Ci32 = x1_i; p.wb32 = 1; p.Crh = x1h_r; p.Cih = x1h_i;
  run_gemm(stream, 0, 0, 1, p, 1);

  // ---- h = gelu(x1 @ Wf1^T + b_f1) ----
  clearp();
  p.M = 2048; p.N = 4096; p.K = 1024; p.lda = 1024; p.ldb = 1024; p.ldc = 4096;
  p.Arh = x1h_r; p.Aih = x1h_i; p.Brh = Wf1_rh; p.Bih = Wf1_ih;
  p.bias_mode = 1; p.biasr = br_f1; p.biasi = bi_f1;
  p.gelu = 1;
  p.Crh = h_r; p.Cih = h_i;
  run_gemm(stream, 0, 0, 1, p, 1);

  // ---- x2 = x1 + h @ Wf2^T + b_f2 (emit x2 hi/lo) ----
  clearp();
  p.M = 2048; p.N = 1024; p.K = 4096; p.lda = 4096; p.ldb = 4096; p.ldc = 1024;
  p.Arh = h_r; p.Aih = h_i; p.Brh = Wf2_rh; p.Bih = Wf2_ih;
  p.bias_mode = 1; p.biasr = br_f2; p.biasi = bi_f2;
  p.Resr = x1_r; p.Resi = x1_i;
  p.Crh = x2_rh; p.Cih = x2_ih; p.Crl = x2_rl; p.Cil = x2_il;
  run_gemm(stream, 0, 0, 1, p, 1);

  // ---- Xh = bf16(H*dt) — NOW safe: scores region dead (PV was last reader) ----
  hipLaunchKernelGGL(cvt_split_kernel, dim3(1024), dim3(256), 0, stream, Hm, Xh,
                     (u16*)nullptr, (i64)1048576, dtp);

  // ---- X2 = X @ X (X symmetric -> NT) ----
  clearp();
  p.M = 1024; p.N = 1024; p.K = 1024; p.lda = 1024; p.ldb = 1024; p.ldc = 1024;
  p.Arh = Xh; p.Brh = Xh;
  p.Cr32 = X2m; p.wb32 = 1;
  run_gemm(stream, 1, 0, 1, p, 1);
  hipLaunchKernelGGL(assemble_U_kernel, dim3(4096), dim3(256), 0, stream, X2m, Hm, dtp, Urh, Uih);

  // ---- out = x2 @ U (U symmetric -> NT), fused split-A single pass ----
  float* out_r = (float*)d_out;
  float* out_i = out_r + 2097152;
  clearp();
  p.M = 2048; p.N = 1024; p.K = 1024; p.lda = 1024; p.ldb = 1024; p.ldc = 1024;
  p.Arh = x2_rh; p.Aih = x2_ih; p.Arl = x2_rl; p.Ail = x2_il;
  p.Brh = Urh; p.Bih = Uih; p.splitB = 0;
  p.Cr32 = out_r; p.Ci32 = out_i; p.wb32 = 1;
  run_gemm(stream, 0, 1, 1, p, 1);
}

// Round 8
// 858.656 us; speedup vs baseline: 1.7017x; 1.0591x over previous
//
#include <hip/hip_runtime.h>
#include <cstdint>
#include <cstddef>

typedef unsigned int u32;
typedef unsigned short u16;
typedef long long i64;

typedef __attribute__((ext_vector_type(8))) short short8;
typedef __attribute__((ext_vector_type(4))) float f32x4;
typedef __attribute__((ext_vector_type(4))) int i32x4;

// ---------------- device helpers ----------------
__device__ __forceinline__ u16 f2bf(float f) {
  u32 u = __float_as_uint(f);
  u = (u + 0x7FFFu + ((u >> 16) & 1u)) >> 16;  // RNE
  return (u16)u;
}
__device__ __forceinline__ float bf2f(u16 h) { return __uint_as_float(((u32)h) << 16); }

__device__ __forceinline__ short8 neg8(short8 v) {
  i32x4 u = __builtin_bit_cast(i32x4, v);
  u = u ^ (int)0x80008000u;
  return __builtin_bit_cast(short8, u);
}
__device__ __forceinline__ f32x4 mfma16(short8 a, short8 b, f32x4 c) {
  return __builtin_amdgcn_mfma_f32_16x16x32_bf16(a, b, c, 0, 0, 0);
}
__device__ __forceinline__ float gelu_f(float x) {
  return 0.5f * x * (1.0f + erff(x * 0.7071067811865475f));
}
// async global->LDS, 16B/lane; LDS dest = wave-uniform base + lane*16 (LINEAR — m104)
__device__ __forceinline__ void gl16(const u16* g, u16* l) {
  __builtin_amdgcn_global_load_lds((const __attribute__((address_space(1))) void*)g,
                                   (__attribute__((address_space(3))) void*)l, 16, 0, 0);
}
// counted vmcnt wait fused with raw barrier: single opaque asm so no memory op
// (ds_read / global_load_lds) can be scheduled across it (rule #18 class hazard).
template <int N>
__device__ __forceinline__ void wait_barrier() {
  asm volatile("s_waitcnt vmcnt(%0)\n\ts_barrier" ::"i"(N) : "memory");
}

// ---------------- generic complex GEMM ----------------
// C[m,n] = sum_k op(A)[m,k] op(B)[n,k]   (B is [N,K] row-major)
// CMODE 0 CMUL : Cr=ArBr-AiBi, Ci=ArBi+AiBr
// CMODE 1 CONJR: Cr=ArBr+AiBi (split) / ArBr (nonsplit real*real)
// CMODE 2 REALA: Cr=A*Br, Ci=A*Bi (A real bf16)
// CMODE 3 CONJA: Cr=ArBr+AiBi, Ci=ArBi-AiBr
//
// R7 PROVEN: blocks/CU (grid-size occupancy) is the binding constraint; 64x64
// tiles at >=2 blocks/CU beat 128x64 at 1 block/CU (909us, Occ 10->28%).
// SPLIT=0 DEEP=1: R7-VERIFIED 64x64 depth-3 nonsplit pipeline (2-3 blocks/CU).
// SPLIT=1 DEEP=1: 64x64 depth-2 full-split (DFT/Q/K): 2x32KB=64KB -> 2 blocks/CU.
//   vmcnt(0) drain per K-step is covered by the co-resident block's compute (TLP).
// SPLIT=1 DEEP=2: 64x64 depth-3 splitB=0 (out): 3x24KB=72KB -> 2 blocks/CU,
//   counted vmcnt (both mechanisms).
// SPLIT=1 DEEP=0: verified single-buffered two-barrier 128x64 loop (scores only).
struct GemmP {
  const u16 *Arh, *Aih, *Arl, *Ail;
  const u16 *Brh, *Bih, *Brl, *Bil;
  const float *biasr, *biasi;
  const float *Resr, *Resi;
  float *Cr32, *Ci32;
  u16 *Crh, *Cih, *Crl, *Cil;
  i64 sA1, sA2, sB1, sB2, sC1, sC2;
  int ZH;
  int M, N, K, lda, ldb, ldc;
  float alpha;
  int beta, wb32, ctrans, bias_mode, bias_period, gelu, splitB;
  float bias_scale;
};

template <int CMODE, int SPLIT, int DEEP>
__global__ __launch_bounds__(256, 2) void cgemm_kernel(GemmP p) {
  constexpr bool HAS_CI = (CMODE == 0 || CMODE == 2 || CMODE == 3);
  constexpr bool AI = (CMODE == 0 || CMODE == 3);
  constexpr bool BIc = (CMODE == 0 || CMODE == 2 || CMODE == 3);
  constexpr bool OLD128 = (SPLIT && DEEP == 0);  // scores path (128x64)
  constexpr int SB = (DEEP == 2) ? 2 : 4;        // staged B comps (split-64)
  // u16 units: scores 48KB; split-64 d2 32KB; split-64 d3 24KB; nonsplit 16KB.
  constexpr int BUFU = SPLIT ? (DEEP == 0 ? 24576 : (DEEP == 2 ? 12288 : 16384)) : 8192;
  constexpr int NBUF = DEEP ? ((SPLIT && DEEP == 1) ? 2 : 3) : 1;
  __shared__ u16 smem[BUFU * NBUF];
  constexpr int LPS64 = 2 + (AI ? 1 : 0) + (BIc ? 1 : 0);  // gl16/stage/wave nonsplit
  constexpr int NJ = OLD128 ? 4 : 2;  // B-fragment count per wave

  const int tid = threadIdx.x, lane = tid & 63, wave = tid >> 6;
  const int lrow = lane & 15, quad = lane >> 4;
  const int wr = wave >> 1, wc = wave & 1;  // 64x64 2x2 wave layout
  const int m0 = blockIdx.y * (OLD128 ? 128 : 64);
  const int n0 = blockIdx.x * 64;
  const int z1 = blockIdx.z / p.ZH, z2 = blockIdx.z % p.ZH;
  const i64 zA = (i64)z1 * p.sA1 + (i64)z2 * p.sA2;
  const i64 zB = (i64)z1 * p.sB1 + (i64)z2 * p.sB2;
  const i64 zC = (i64)z1 * p.sC1 + (i64)z2 * p.sC2;
  const int l4 = lane >> 2;
  // DEEP: pre-swizzled global source chunk (both-sides-or-neither, m104/m231):
  // LDS slot (row r, chunk c) holds logical chunk c ^ ((r>>1)&3); reads XOR same term.
  const int lc = DEEP ? ((((lane & 3) ^ ((lane >> 3) & 3))) << 3) : ((lane & 3) << 3);
  // scores: each wave stages 32 A-rows (two groups); others: 16 rows.
  const i64 aoff0 = zA + (i64)(m0 + (OLD128 ? 32 : 16) * wave + l4) * p.lda + lc;
  const i64 aoff1 = aoff0 + (i64)16 * p.lda;  // scores only
  const i64 boff = zB + (i64)(n0 + 16 * wave + l4) * p.ldb + lc;
  const int lA0 = (OLD128 ? 1024 : 512) * wave, lA1 = lA0 + 512;
  const int lB0 = 512 * wave;
  const int cxw = ((lrow >> 1) & 3) << 3;  // read-side swizzle XOR (u16 units)

  f32x4 accR[2][NJ], accI[2][NJ];
  const f32x4 z4 = {0.f, 0.f, 0.f, 0.f};
#pragma unroll
  for (int i = 0; i < 2; ++i)
#pragma unroll
    for (int j = 0; j < NJ; ++j) { accR[i][j] = z4; accI[i][j] = z4; }

  const int ktn = p.K >> 5;

  if constexpr (SPLIT && DEEP == 0) {
    // ---- verified single-buffered two-barrier loop (scores path, 128x64) ----
    for (int kt = 0; kt < ktn; ++kt) {
      const i64 kc = (i64)(kt << 5);
      __syncthreads();  // all waves done reading previous tile
      gl16(p.Arh + aoff0 + kc, smem + lA0);
      gl16(p.Arh + aoff1 + kc, smem + lA1);
      gl16(p.Aih + aoff0 + kc, smem + 4096 + lA0);
      gl16(p.Aih + aoff1 + kc, smem + 4096 + lA1);
      gl16(p.Arl + aoff0 + kc, smem + 8192 + lA0);
      gl16(p.Arl + aoff1 + kc, smem + 8192 + lA1);
      gl16(p.Ail + aoff0 + kc, smem + 12288 + lA0);
      gl16(p.Ail + aoff1 + kc, smem + 12288 + lA1);
      gl16(p.Brh + boff + kc, smem + 16384 + lB0);
      gl16(p.Bih + boff + kc, smem + 18432 + lB0);
      if (p.splitB) {
        gl16(p.Brl + boff + kc, smem + 20480 + lB0);
        gl16(p.Bil + boff + kc, smem + 22528 + lB0);
      }
      __syncthreads();  // drains vmcnt -> DMA landed

      short8 bRh[4], bIh[4], bRl[4], bIl[4];
#pragma unroll
      for (int j = 0; j < 4; ++j) {
        const int off = (j * 16 + lrow) * 32 + quad * 8;
        bRh[j] = *(const short8*)&smem[16384 + off];
        bIh[j] = *(const short8*)&smem[18432 + off];
        if (p.splitB) {
          bRl[j] = *(const short8*)&smem[20480 + off];
          bIl[j] = *(const short8*)&smem[22528 + off];
        }
      }
#pragma unroll
      for (int i = 0; i < 2; ++i) {
        const int off = (wave * 32 + i * 16 + lrow) * 32 + quad * 8;
        short8 aRh = *(const short8*)&smem[off];
        short8 aIh = *(const short8*)&smem[4096 + off];
        short8 aRl = *(const short8*)&smem[8192 + off];
        short8 aIl = *(const short8*)&smem[12288 + off];
        if constexpr (CMODE == 0) {
          short8 nIh = neg8(aIh), nIl = neg8(aIl);
#pragma unroll
          for (int j = 0; j < 4; ++j) {
            accR[i][j] = mfma16(aRh, bRh[j], accR[i][j]);
            accR[i][j] = mfma16(nIh, bIh[j], accR[i][j]);
            accI[i][j] = mfma16(aRh, bIh[j], accI[i][j]);
            accI[i][j] = mfma16(aIh, bRh[j], accI[i][j]);
            accR[i][j] = mfma16(aRl, bRh[j], accR[i][j]);
            accR[i][j] = mfma16(nIl, bIh[j], accR[i][j]);
            accI[i][j] = mfma16(aRl, bIh[j], accI[i][j]);
            accI[i][j] = mfma16(aIl, bRh[j], accI[i][j]);
            if (p.splitB) {
              accR[i][j] = mfma16(aRh, bRl[j], accR[i][j]);
              accR[i][j] = mfma16(nIh, bIl[j], accR[i][j]);
              accI[i][j] = mfma16(aRh, bIl[j], accI[i][j]);
              accI[i][j] = mfma16(aIh, bRl[j], accI[i][j]);
            }
          }
        } else {  // CONJR split: Re(Q conj(K)) 3-combo
#pragma unroll
          for (int j = 0; j < 4; ++j) {
            accR[i][j] = mfma16(aRh, bRh[j], accR[i][j]);
            accR[i][j] = mfma16(aIh, bIh[j], accR[i][j]);
            accR[i][j] = mfma16(aRl, bRh[j], accR[i][j]);
            accR[i][j] = mfma16(aIl, bIh[j], accR[i][j]);
            accR[i][j] = mfma16(aRh, bRl[j], accR[i][j]);
            accR[i][j] = mfma16(aIh, bIl[j], accR[i][j]);
          }
        }
      }
    }
  } else if constexpr (SPLIT && DEEP >= 1) {
    // ---- 64x64 split tile. Buffer layout (u16): A rh 0, ih +2048, rl +4096,
    // il +6144; B rh +8192, ih +10240 [, rl +12288, il +14336 when SB==4].
    // DEEP==1: depth-2, vmcnt(0) drain covered by co-resident block (2 blocks/CU).
    // DEEP==2: depth-3, counted vmcnt (6 gl16/stage), splitB=0.
    auto stageS = [&](int buf, i64 kc) {
      u16* s = smem + buf * BUFU;
      gl16(p.Arh + aoff0 + kc, s + lA0);
      gl16(p.Aih + aoff0 + kc, s + 2048 + lA0);
      gl16(p.Arl + aoff0 + kc, s + 4096 + lA0);
      gl16(p.Ail + aoff0 + kc, s + 6144 + lA0);
      gl16(p.Brh + boff + kc, s + 8192 + lB0);
      gl16(p.Bih + boff + kc, s + 10240 + lB0);
      if constexpr (SB == 4) {
        gl16(p.Brl + boff + kc, s + 12288 + lB0);
        gl16(p.Bil + boff + kc, s + 14336 + lB0);
      }
    };
    if (ktn > 0) stageS(0, 0);
    if (DEEP == 2 && ktn > 1) stageS(1, 32);
    for (int kt = 0; kt < ktn; ++kt) {
      if constexpr (DEEP == 1) {
        wait_barrier<0>();  // stage(kt) landed (issued 1 compute-phase ago) + sync
        if (kt + 1 < ktn) stageS((kt + 1) & 1, (i64)((kt + 1) << 5));
      } else {
        if (kt + 1 < ktn) wait_barrier<6>(); else wait_barrier<0>();
        if (kt + 2 < ktn) stageS((kt + 2) % 3, (i64)((kt + 2) << 5));
      }
      const u16* sb = smem + (DEEP == 1 ? (kt & 1) : (kt % 3)) * BUFU;

      short8 bRh[2], bIh[2], bRl[2], bIl[2];
#pragma unroll
      for (int j = 0; j < 2; ++j) {
        const int off = 8192 + (wc * 32 + j * 16 + lrow) * 32 + (quad * 8 ^ cxw);
        bRh[j] = *(const short8*)&sb[off];
        bIh[j] = *(const short8*)&sb[off + 2048];
        if constexpr (SB == 4) {
          bRl[j] = *(const short8*)&sb[off + 4096];
          bIl[j] = *(const short8*)&sb[off + 6144];
        }
      }
#pragma unroll
      for (int i = 0; i < 2; ++i) {
        const int off = (wr * 32 + i * 16 + lrow) * 32 + (quad * 8 ^ cxw);
        short8 aRh = *(const short8*)&sb[off];
        short8 aIh = *(const short8*)&sb[off + 2048];
        short8 aRl = *(const short8*)&sb[off + 4096];
        short8 aIl = *(const short8*)&sb[off + 6144];
        short8 nIh = neg8(aIh), nIl = neg8(aIl);
#pragma unroll
        for (int j = 0; j < 2; ++j) {
          accR[i][j] = mfma16(aRh, bRh[j], accR[i][j]);
          accR[i][j] = mfma16(nIh, bIh[j], accR[i][j]);
          accI[i][j] = mfma16(aRh, bIh[j], accI[i][j]);
          accI[i][j] = mfma16(aIh, bRh[j], accI[i][j]);
          accR[i][j] = mfma16(aRl, bRh[j], accR[i][j]);
          accR[i][j] = mfma16(nIl, bIh[j], accR[i][j]);
          accI[i][j] = mfma16(aRl, bIh[j], accI[i][j]);
          accI[i][j] = mfma16(aIl, bRh[j], accI[i][j]);
          if constexpr (SB == 4) {
            accR[i][j] = mfma16(aRh, bRl[j], accR[i][j]);
            accR[i][j] = mfma16(nIh, bIl[j], accR[i][j]);
            accI[i][j] = mfma16(aRh, bIl[j], accI[i][j]);
            accI[i][j] = mfma16(aIh, bRl[j], accI[i][j]);
          }
        }
      }
    }
  } else {
    // ---- R7-VERIFIED 64x64-tile nonsplit depth-3 pipeline ----
    // buffer (u16): A_r +0, A_i +2048, B_r +4096, B_i +6144.
    auto stage = [&](int buf, i64 kc) {
      u16* s = smem + buf * 8192;
      gl16(p.Arh + aoff0 + kc, s + lA0);
      if constexpr (AI) gl16(p.Aih + aoff0 + kc, s + 2048 + lA0);
      gl16(p.Brh + boff + kc, s + 4096 + lB0);
      if constexpr (BIc) gl16(p.Bih + boff + kc, s + 6144 + lB0);
    };
    if (ktn > 0) stage(0, 0);
    if (ktn > 1) stage(1, 32);
    for (int kt = 0; kt < ktn; ++kt) {
      if (kt + 1 < ktn) wait_barrier<LPS64>(); else wait_barrier<0>();
      if (kt + 2 < ktn) stage((kt + 2) % 3, (i64)((kt + 2) << 5));
      const u16* sb = smem + (kt % 3) * 8192;

      short8 bR[2], bI[2];
#pragma unroll
      for (int j = 0; j < 2; ++j) {
        const int off = 4096 + (wc * 32 + j * 16 + lrow) * 32 + (quad * 8 ^ cxw);
        bR[j] = *(const short8*)&sb[off];
        if constexpr (BIc) bI[j] = *(const short8*)&sb[off + 2048];
      }
#pragma unroll
      for (int i = 0; i < 2; ++i) {
        const int off = (wr * 32 + i * 16 + lrow) * 32 + (quad * 8 ^ cxw);
        short8 aR = *(const short8*)&sb[off];
        if constexpr (CMODE == 0) {
          short8 aI = *(const short8*)&sb[off + 2048];
          short8 nI = neg8(aI);
#pragma unroll
          for (int j = 0; j < 2; ++j) {
            accR[i][j] = mfma16(aR, bR[j], accR[i][j]);
            accR[i][j] = mfma16(nI, bI[j], accR[i][j]);
            accI[i][j] = mfma16(aR, bI[j], accI[i][j]);
            accI[i][j] = mfma16(aI, bR[j], accI[i][j]);
          }
        } else if constexpr (CMODE == 1) {  // real*real
#pragma unroll
          for (int j = 0; j < 2; ++j) accR[i][j] = mfma16(aR, bR[j], accR[i][j]);
        } else if constexpr (CMODE == 2) {  // A real, B complex
#pragma unroll
          for (int j = 0; j < 2; ++j) {
            accR[i][j] = mfma16(aR, bR[j], accR[i][j]);
            accI[i][j] = mfma16(aR, bI[j], accI[i][j]);
          }
        } else {  // CONJA
          short8 aI = *(const short8*)&sb[off + 2048];
          short8 nI = neg8(aI);
#pragma unroll
          for (int j = 0; j < 2; ++j) {
            accR[i][j] = mfma16(aR, bR[j], accR[i][j]);
            accR[i][j] = mfma16(aI, bI[j], accR[i][j]);
            accI[i][j] = mfma16(aR, bI[j], accI[i][j]);
            accI[i][j] = mfma16(nI, bR[j], accI[i][j]);
          }
        }
      }
    }
  }

  // ---- epilogue ----
#pragma unroll
  for (int i = 0; i < 2; ++i) {
#pragma unroll
    for (int j = 0; j < NJ; ++j) {
      const int gn = OLD128 ? (n0 + j * 16 + lrow) : (n0 + wc * 32 + j * 16 + lrow);
#pragma unroll
      for (int r = 0; r < 4; ++r) {
        const int gm = OLD128 ? (m0 + wave * 32 + i * 16 + quad * 4 + r)
                              : (m0 + wr * 32 + i * 16 + quad * 4 + r);
        const i64 idx = p.ctrans ? (zC + (i64)gn * p.ldc + gm) : (zC + (i64)gm * p.ldc + gn);
        float vr = accR[i][j][r] * p.alpha;
        float vi = 0.f;
        if (HAS_CI) vi = accI[i][j][r] * p.alpha;
        if (p.beta) {
          vr += p.Cr32[idx];
          if (HAS_CI && p.Ci32) vi += p.Ci32[idx];
        }
        if (p.bias_mode == 1) {
          vr += p.biasr[gn];
          if (HAS_CI) vi += p.biasi[gn];
        } else if (p.bias_mode == 2) {
          if ((gm % p.bias_period) == 0) {
            vr += p.biasr[gn] * p.bias_scale;
            if (HAS_CI) vi += p.biasi[gn] * p.bias_scale;
          }
        }
        if (p.Resr) vr += p.Resr[idx];
        if (HAS_CI && p.Resi) vi += p.Resi[idx];
        if (p.gelu) {
          vr = gelu_f(vr);
          if (HAS_CI) vi = gelu_f(vi);
        }
        if (p.wb32 && p.Cr32) p.Cr32[idx] = vr;
        if (p.wb32 && HAS_CI && p.Ci32) p.Ci32[idx] = vi;
        if (p.Crh) {
          const u16 hh = f2bf(vr);
          p.Crh[idx] = hh;
          if (p.Crl) p.Crl[idx] = f2bf(vr - bf2f(hh));
        }
        if (HAS_CI && p.Cih) {
          const u16 hh = f2bf(vi);
          p.Cih[idx] = hh;
          if (p.Cil) p.Cil[idx] = f2bf(vi - bf2f(hh));
        }
      }
    }
  }
}

// ---------------- pointwise kernels ----------------
struct CvtBatch {
  const float* src[12];
  u16* hi[12];
  u16* lo[12];
  i64 cum[13];
};
__global__ __launch_bounds__(256) void cvt_batch_kernel(CvtBatch b) {
  const i64 k = (i64)blockIdx.x * 1024 + (i64)threadIdx.x * 4;
  int s = 0;
  while (k >= b.cum[s + 1]) ++s;  // all segment sizes are multiples of 1024
  const i64 base = k - b.cum[s];
  float4 v = *(const float4*)(b.src[s] + base);
  u16* hp = b.hi[s];
  u16* lp = b.lo[s];
  ushort4 h, l;
  h.x = f2bf(v.x); l.x = f2bf(v.x - bf2f(h.x));
  h.y = f2bf(v.y); l.y = f2bf(v.y - bf2f(h.y));
  h.z = f2bf(v.z); l.z = f2bf(v.z - bf2f(h.z));
  h.w = f2bf(v.w); l.w = f2bf(v.w - bf2f(h.w));
  *(ushort4*)(hp + base) = h;
  if (lp) *(ushort4*)(lp + base) = l;
}

// standalone convert (used for Hm -> Xh AFTER scores region is dead — liveness invariant!)
__global__ __launch_bounds__(256) void cvt_split_kernel(const float* in, u16* hi, u16* lo,
                                                        i64 n, const float* scale_ptr) {
  const i64 base = (i64)blockIdx.x * 1024 + (i64)threadIdx.x * 4;
  const float s = scale_ptr ? *scale_ptr : 1.0f;
#pragma unroll
  for (int e = 0; e < 4; ++e) {
    const i64 k = base + e;
    if (k < n) {
      const float v = in[k] * s;
      const u16 h = f2bf(v);
      hi[k] = h;
      if (lo) lo[k] = f2bf(v - bf2f(h));
    }
  }
}

// x[b][j][d] fp32 -> xT[b][d][j] bf16 hi/lo  (32x32 LDS tile transpose)
__global__ __launch_bounds__(256) void trans_cvt_kernel(const float* in, u16* outh, u16* outl) {
  __shared__ float t[32][33];
  const int b = blockIdx.z;
  const int j0 = blockIdx.y * 32;
  const int d0 = blockIdx.x * 32;
  const int r = threadIdx.x >> 5, c = threadIdx.x & 31;
  const float* ip = in + (i64)b * 1048576;
#pragma unroll
  for (int it = 0; it < 4; ++it) t[r + it * 8][c] = ip[(i64)(j0 + r + it * 8) * 1024 + d0 + c];
  __syncthreads();
  u16* ohp = outh + (i64)b * 1048576;
  u16* olp = outl + (i64)b * 1048576;
#pragma unroll
  for (int it = 0; it < 4; ++it) {
    const float v = t[c][r + it * 8];
    const i64 o = (i64)(d0 + r + it * 8) * 1024 + j0 + c;
    const u16 h = f2bf(v);
    ohp[o] = h;
    olp[o] = f2bf(v - bf2f(h));
  }
}

__global__ __launch_bounds__(256) void gen_F_kernel(u16* Frh, u16* Frl, u16* Fih, u16* Fil) {
  const int idx = blockIdx.x * 256 + threadIdx.x;
  const int mm = idx >> 10, kk = idx & 1023;
  const int t = (mm * kk) & 1023;
  float sv, cv;
  sincosf((float)t * 6.135923151e-3f, &sv, &cv);  // 2*pi/1024
  const float fr = cv, fi = -sv;
  u16 h = f2bf(fr);
  Frh[idx] = h;
  Frl[idx] = f2bf(fr - bf2f(h));
  h = f2bf(fi);
  Fih[idx] = h;
  Fil[idx] = f2bf(fi - bf2f(h));
}

// U = expm(-iHdt) ~ (I - X^2/2) + i(-X), X=H dt (X^3/6 term ~1e-6 el, dropped)
__global__ __launch_bounds__(256) void assemble_U_kernel(const float* X2m, const float* Hm,
                                                         const float* dtp, u16* Urh, u16* Uih) {
  const int idx = blockIdx.x * 256 + threadIdx.x;
  const int i = idx >> 10, j = idx & 1023;
  const float dt = *dtp;
  const float ur = ((i == j) ? 1.0f : 0.0f) - 0.5f * X2m[idx];
  const float ui = -dt * Hm[idx];
  Urh[idx] = f2bf(ur);
  Uih[idx] = f2bf(ui);
}

// softmax over 1024 fp32, writes bf16 probs in-place at row start (row stride stays 4KB)
__global__ __launch_bounds__(256) void softmax_kernel(float* S) {
  float* row = S + (i64)blockIdx.x * 1024;
  const int t = threadIdx.x;
  float4 v = *(float4*)(row + t * 4);
  float m = fmaxf(fmaxf(v.x, v.y), fmaxf(v.z, v.w));
#pragma unroll
  for (int off = 32; off > 0; off >>= 1) m = fmaxf(m, __shfl_down(m, off));
  __shared__ float red[8];
  const int lane = t & 63, w = t >> 6;
  if (lane == 0) red[w] = m;
  __syncthreads();
  if (t == 0) red[4] = fmaxf(fmaxf(red[0], red[1]), fmaxf(red[2], red[3]));
  __syncthreads();
  m = red[4];
  v.x = expf(v.x - m);
  v.y = expf(v.y - m);
  v.z = expf(v.z - m);
  v.w = expf(v.w - m);
  float s = v.x + v.y + v.z + v.w;
#pragma unroll
  for (int off = 32; off > 0; off >>= 1) s += __shfl_down(s, off);
  if (lane == 0) red[w] = s;
  __syncthreads();
  if (t == 0) red[5] = red[0] + red[1] + red[2] + red[3];
  __syncthreads();
  const float inv = 1.0f / red[5];
  ushort4 o;
  o.x = f2bf(v.x * inv);
  o.y = f2bf(v.y * inv);
  o.z = f2bf(v.z * inv);
  o.w = f2bf(v.w * inv);
  *(ushort4*)((u16*)row + t * 4) = o;
}

// ---------------- host side ----------------
static void run_gemm(hipStream_t s, int cmode, int split, int deep, const GemmP& p, int Z) {
  // scores (split,deep=0): 128-row tiles; everything else: 64-row tiles.
  const int mshift = (split && deep == 0) ? 7 : 6;
  dim3 g((unsigned)(p.N >> 6), (unsigned)(p.M >> mshift), (unsigned)Z);
  dim3 b(256, 1, 1);
  if (split) {
    if (deep == 1) hipLaunchKernelGGL(HIP_KERNEL_NAME(cgemm_kernel<0, 1, 1>), g, b, 0, s, p);
    else if (deep == 2) hipLaunchKernelGGL(HIP_KERNEL_NAME(cgemm_kernel<0, 1, 2>), g, b, 0, s, p);
    else hipLaunchKernelGGL(HIP_KERNEL_NAME(cgemm_kernel<1, 1, 0>), g, b, 0, s, p);
  } else {
    if (cmode == 0) hipLaunchKernelGGL(HIP_KERNEL_NAME(cgemm_kernel<0, 0, 1>), g, b, 0, s, p);
    else if (cmode == 1) hipLaunchKernelGGL(HIP_KERNEL_NAME(cgemm_kernel<1, 0, 1>), g, b, 0, s, p);
    else if (cmode == 2) hipLaunchKernelGGL(HIP_KERNEL_NAME(cgemm_kernel<2, 0, 1>), g, b, 0, s, p);
    else hipLaunchKernelGGL(HIP_KERNEL_NAME(cgemm_kernel<3, 0, 1>), g, b, 0, s, p);
  }
}

extern "C" void kernel_launch(void* const* d_in, const int* in_sizes, int n_in, void* d_out,
                              int out_size, void* d_ws, size_t ws_size, hipStream_t stream) {
  (void)in_sizes; (void)n_in; (void)out_size; (void)ws_size;
  const float* x_real = (const float*)d_in[0];
  const float* x_imag = (const float*)d_in[1];
  const float* Wr_q = (const float*)d_in[2];
  const float* Wi_q = (const float*)d_in[3];
  const float* br_q = (const float*)d_in[4];
  const float* bi_q = (const float*)d_in[5];
  const float* Wr_k = (const float*)d_in[6];
  const float* Wi_k = (const float*)d_in[7];
  const float* br_k = (const float*)d_in[8];
  const float* bi_k = (const float*)d_in[9];
  const float* Wr_v = (const float*)d_in[10];
  const float* Wi_v = (const float*)d_in[11];
  const float* br_v = (const float*)d_in[12];
  const float* bi_v = (const float*)d_in[13];
  const float* Wr_o = (const float*)d_in[14];
  const float* Wi_o = (const float*)d_in[15];
  const float* br_o = (const float*)d_in[16];
  const float* bi_o = (const float*)d_in[17];
  const float* Wr_f1 = (const float*)d_in[18];
  const float* Wi_f1 = (const float*)d_in[19];
  const float* br_f1 = (const float*)d_in[20];
  const float* bi_f1 = (const float*)d_in[21];
  const float* Wr_f2 = (const float*)d_in[22];
  const float* Wi_f2 = (const float*)d_in[23];
  const float* br_f2 = (const float*)d_in[24];
  const float* bi_f2 = (const float*)d_in[25];
  const float* Hm = (const float*)d_in[26];
  const float* dtp = (const float*)d_in[27];

  const size_t MBy = 1ull << 20;
  char* W = (char*)d_ws;
  auto U16 = [&](size_t mb) { return (u16*)(W + mb * MBy); };
  auto F32p = [&](size_t mb) { return (float*)(W + mb * MBy); };

  // zone 1 [0,128MB): scores fp32 region, time-shared with transients.
  // LIVENESS INVARIANT: anything here that is READ after the scores GEMM must be
  // WRITTEN after PV (last scores reader). Xh/X2m/U obey this (written post-f2).
  float* scores = F32p(0);
  u16 *xT_rh = U16(0), *xT_ih = U16(4), *xT_rl = U16(8), *xT_il = U16(12);
  u16 *Wq_rh = U16(16), *Wq_ih = U16(18), *Wq_rl = U16(20), *Wq_il = U16(22);
  u16 *Wk_rh = U16(24), *Wk_ih = U16(26), *Wk_rl = U16(28), *Wk_il = U16(30);
  u16 *xf_rh = U16(32), *xf_ih = U16(36), *xf_rl = U16(40), *xf_il = U16(44);
  u16 *h_r = U16(64), *h_i = U16(80);
  u16 *x2_rh = U16(96), *x2_ih = U16(100), *x2_rl = U16(104), *x2_il = U16(108);
  u16* Xh = U16(112);
  float* X2m = F32p(114);
  u16 *Urh = U16(124), *Uih = U16(126);
  // zone 2 [128MB,256MB): persistent
  u16 *Wv_rh = U16(128), *Wv_ih = U16(130);
  u16 *Wo_rh = U16(132), *Wo_ih = U16(134);
  u16 *Wf1_rh = U16(136), *Wf1_ih = U16(144);
  u16 *Wf2_rh = U16(152), *Wf2_ih = U16(160);
  u16 *F_rh = U16(168), *F_ih = U16(170), *F_rl = U16(172), *F_il = U16(174);
  u16 *Qf_rh = U16(176), *Qf_ih = U16(180), *Qf_rl = U16(184), *Qf_il = U16(188);
  u16 *Kf_rh = U16(192), *Kf_ih = U16(196), *Kf_rl = U16(200), *Kf_il = U16(204);
  u16 *VfT_r = U16(208), *VfT_i = U16(212);  // [b][d][seq]
  u16 *ofT_r = U16(216), *ofT_i = U16(220);  // [b][d][seq]
  u16 *ot_r = U16(224), *ot_i = U16(228);    // [b*seq][d]
  float* x1_r = F32p(232);
  float* x1_i = F32p(240);
  u16 *x1h_r = U16(248), *x1h_i = U16(252);

  // ---- batched conversions (weights ONLY — Hm deferred past scores lifetime) ----
  {
    CvtBatch b{};
    const float* srcs[12] = {Wr_q, Wi_q, Wr_k, Wi_k, Wr_v, Wi_v, Wr_o, Wi_o,
                             Wr_f1, Wi_f1, Wr_f2, Wi_f2};
    u16* his[12] = {Wq_rh, Wq_ih, Wk_rh, Wk_ih, Wv_rh, Wv_ih, Wo_rh, Wo_ih,
                    Wf1_rh, Wf1_ih, Wf2_rh, Wf2_ih};
    u16* los[12] = {Wq_rl, Wq_il, Wk_rl, Wk_il, nullptr, nullptr, nullptr, nullptr,
                    nullptr, nullptr, nullptr, nullptr};
    const i64 sizes[12] = {1048576, 1048576, 1048576, 1048576, 1048576, 1048576, 1048576,
                           1048576, 4194304, 4194304, 4194304, 4194304};
    i64 c = 0;
    for (int i = 0; i < 12; ++i) {
      b.src[i] = srcs[i]; b.hi[i] = his[i]; b.lo[i] = los[i];
      b.cum[i] = c; c += sizes[i];
    }
    b.cum[12] = c;
    hipLaunchKernelGGL(cvt_batch_kernel, dim3((unsigned)(c / 1024)), dim3(256), 0, stream, b);
  }
  hipLaunchKernelGGL(trans_cvt_kernel, dim3(32, 32, 2), dim3(256), 0, stream, x_real, xT_rh, xT_rl);
  hipLaunchKernelGGL(trans_cvt_kernel, dim3(32, 32, 2), dim3(256), 0, stream, x_imag, xT_ih, xT_il);
  hipLaunchKernelGGL(gen_F_kernel, dim3(4096), dim3(256), 0, stream, F_rh, F_rl, F_ih, F_il);

  GemmP p;
  auto clearp = [&]() {
    p = GemmP{};
    p.alpha = 1.0f;
    p.ZH = 1;
  };

  // ---- DFT: xf[b] = F @ x[b], fused bf16x2 (A=F h/l, B=xT h/l) ----
  clearp();
  p.M = 1024; p.N = 1024; p.K = 1024; p.lda = 1024; p.ldb = 1024; p.ldc = 1024;
  p.sB1 = 1048576; p.sC1 = 1048576;
  p.Arh = F_rh; p.Aih = F_ih; p.Arl = F_rl; p.Ail = F_il;
  p.Brh = xT_rh; p.Bih = xT_ih; p.Brl = xT_rl; p.Bil = xT_il; p.splitB = 1;
  p.Crh = xf_rh; p.Cih = xf_ih; p.Crl = xf_rl; p.Cil = xf_il;
  run_gemm(stream, 0, 1, 1, p, 2);

  // ---- Q/K projections, fused bf16x2 ----
  auto proj = [&](const u16* Wrh, const u16* Wih, const u16* Wrl, const u16* Wil,
                  const float* br, const float* bi, u16* Orh, u16* Oih, u16* Orl, u16* Oil) {
    clearp();
    p.M = 2048; p.N = 1024; p.K = 1024; p.lda = 1024; p.ldb = 1024; p.ldc = 1024;
    p.Arh = xf_rh; p.Aih = xf_ih; p.Arl = xf_rl; p.Ail = xf_il;
    p.Brh = Wrh; p.Bih = Wih; p.Brl = Wrl; p.Bil = Wil; p.splitB = 1;
    p.bias_mode = 2; p.bias_period = 1024; p.bias_scale = 1024.0f;
    p.biasr = br; p.biasi = bi;
    p.Crh = Orh; p.Cih = Oih; p.Crl = Orl; p.Cil = Oil;
    run_gemm(stream, 0, 1, 1, p, 1);
  };
  proj(Wq_rh, Wq_ih, Wq_rl, Wq_il, br_q, bi_q, Qf_rh, Qf_ih, Qf_rl, Qf_il);
  proj(Wk_rh, Wk_ih, Wk_rl, Wk_il, br_k, bi_k, Kf_rh, Kf_ih, Kf_rl, Kf_il);

  // ---- V projection (plain), TRANSPOSED output VfT[b][d][seq] ----
  clearp();
  p.M = 1024; p.N = 1024; p.K = 1024; p.lda = 1024; p.ldb = 1024; p.ldc = 1024;
  p.sA1 = 1048576; p.sC1 = 1048576;
  p.Arh = xf_rh; p.Aih = xf_ih; p.Brh = Wv_rh; p.Bih = Wv_ih;
  p.bias_mode = 2; p.bias_period = 1024; p.bias_scale = 1024.0f;
  p.biasr = br_v; p.biasi = bi_v;
  p.ctrans = 1;
  p.Crh = VfT_r; p.Cih = VfT_i;
  run_gemm(stream, 0, 0, 1, p, 2);

  // ---- scores = 0.125 * Re(Qf conj(Kf)^T) per head, fused bf16x2 ----
  clearp();
  p.M = 1024; p.N = 1024; p.K = 64; p.lda = 1024; p.ldb = 1024; p.ldc = 1024;
  p.ZH = 16;
  p.sA1 = 1048576; p.sA2 = 64; p.sB1 = 1048576; p.sB2 = 64;
  p.sC1 = 16ll * 1048576; p.sC2 = 1048576;
  p.alpha = 0.125f;
  p.Arh = Qf_rh; p.Aih = Qf_ih; p.Arl = Qf_rl; p.Ail = Qf_il;
  p.Brh = Kf_rh; p.Bih = Kf_ih; p.Brl = Kf_rl; p.Bil = Kf_il; p.splitB = 1;
  p.Cr32 = scores; p.wb32 = 1;
  run_gemm(stream, 1, 1, 0, p, 32);

  hipLaunchKernelGGL(softmax_kernel, dim3(32768), dim3(256), 0, stream, scores);

  // ---- PV: out_f = P @ Vf, P bf16 in-place (lda u16 = 2048), out transposed ofT ----
  clearp();
  p.M = 1024; p.N = 64; p.K = 1024; p.lda = 2048; p.ldb = 1024; p.ldc = 1024;
  p.ZH = 16;
  p.sA1 = 16ll * 2097152; p.sA2 = 2097152;
  p.sB1 = 1048576; p.sB2 = 65536;
  p.sC1 = 1048576; p.sC2 = 65536;
  p.ctrans = 1;
  p.Arh = (const u16*)scores; p.Brh = VfT_r; p.Bih = VfT_i;
  p.Crh = ofT_r; p.Cih = ofT_i;
  run_gemm(stream, 2, 0, 1, p, 32);

  // ---- IDFT: ot[b] = (1/N) conj(F) @ of[b] ----
  clearp();
  p.M = 1024; p.N = 1024; p.K = 1024; p.lda = 1024; p.ldb = 1024; p.ldc = 1024;
  p.sB1 = 1048576; p.sC1 = 1048576;
  p.alpha = 1.0f / 1024.0f;
  p.Arh = F_rh; p.Aih = F_ih; p.Brh = ofT_r; p.Bih = ofT_i;
  p.Crh = ot_r; p.Cih = ot_i;
  run_gemm(stream, 3, 0, 1, p, 2);

  // ---- x1 = x + ot @ Wo^T + b_o ----
  clearp();
  p.M = 2048; p.N = 1024; p.K = 1024; p.lda = 1024; p.ldb = 1024; p.ldc = 1024;
  p.Arh = ot_r; p.Aih = ot_i; p.Brh = Wo_rh; p.Bih = Wo_ih;
  p.bias_mode = 1; p.biasr = br_o; p.biasi = bi_o;
  p.Resr = x_real; p.Resi = x_imag;
  p.Cr32 = x1_r; p.Ci32 = x1_i; p.wb32 = 1; p.Crh = x1h_r; p.Cih = x1h_i;
  run_gemm(stream, 0, 0, 1, p, 1);

  // ---- h = gelu(x1 @ Wf1^T + b_f1) ----
  clearp();
  p.M = 2048; p.N = 4096; p.K = 1024; p.lda = 1024; p.ldb = 1024; p.ldc = 4096;
  p.Arh = x1h_r; p.Aih = x1h_i; p.Brh = Wf1_rh; p.Bih = Wf1_ih;
  p.bias_mode = 1; p.biasr = br_f1; p.biasi = bi_f1;
  p.gelu = 1;
  p.Crh = h_r; p.Cih = h_i;
  run_gemm(stream, 0, 0, 1, p, 1);

  // ---- x2 = x1 + h @ Wf2^T + b_f2 (emit x2 hi/lo) ----
  clearp();
  p.M = 2048; p.N = 1024; p.K = 4096; p.lda = 4096; p.ldb = 4096; p.ldc = 1024;
  p.Arh = h_r; p.Aih = h_i; p.Brh = Wf2_rh; p.Bih = Wf2_ih;
  p.bias_mode = 1; p.biasr = br_f2; p.biasi = bi_f2;
  p.Resr = x1_r; p.Resi = x1_i;
  p.Crh = x2_rh; p.Cih = x2_ih; p.Crl = x2_rl; p.Cil = x2_il;
  run_gemm(stream, 0, 0, 1, p, 1);

  // ---- Xh = bf16(H*dt) — NOW safe: scores region dead (PV was last reader) ----
  hipLaunchKernelGGL(cvt_split_kernel, dim3(1024), dim3(256), 0, stream, Hm, Xh,
                     (u16*)nullptr, (i64)1048576, dtp);

  // ---- X2 = X @ X (X symmetric -> NT) ----
  clearp();
  p.M = 1024; p.N = 1024; p.K = 1024; p.lda = 1024; p.ldb = 1024; p.ldc = 1024;
  p.Arh = Xh; p.Brh = Xh;
  p.Cr32 = X2m; p.wb32 = 1;
  run_gemm(stream, 1, 0, 1, p, 1);
  hipLaunchKernelGGL(assemble_U_kernel, dim3(4096), dim3(256), 0, stream, X2m, Hm, dtp, Urh, Uih);

  // ---- out = x2 @ U (U symmetric -> NT), fused split-A, splitB=0 -> depth-3 ----
  float* out_r = (float*)d_out;
  float* out_i = out_r + 2097152;
  clearp();
  p.M = 2048; p.N = 1024; p.K = 1024; p.lda = 1024; p.ldb = 1024; p.ldc = 1024;
  p.Arh = x2_rh; p.Aih = x2_ih; p.Arl = x2_rl; p.Ail = x2_il;
  p.Brh = Urh; p.Bih = Uih; p.splitB = 0;
  p.Cr32 = out_r; p.Ci32 = out_i; p.wb32 = 1;
  run_gemm(stream, 0, 1, 2, p, 1);
}